// Round 5
// baseline (4803.269 us; speedup 1.0000x reference)
//
#include <hip/hip_runtime.h>
#include <hip/hip_bf16.h>

#define N_NODES 100000
#define N_EDGES 400000
#define NB      4096
#define FAT     30
#define FBOND   11
#define HDIM    256
#define NLAY    5

typedef short s8v  __attribute__((ext_vector_type(8)));
typedef float f32x4 __attribute__((ext_vector_type(4)));

static __device__ __forceinline__ float sigmoidf_(float x){ return 1.0f/(1.0f+expf(-x)); }
static __device__ __forceinline__ float bf2f(short s){
  return __uint_as_float(((unsigned)(unsigned short)s) << 16);
}
static __device__ __forceinline__ short f2bf(float f){   // RNE
  unsigned u = __float_as_uint(f);
  u += 0x7fffu + ((u >> 16) & 1u);
  return (short)(u >> 16);
}

// ---------------- sentinel (ws too small diagnostic) ----------------
__global__ void sentinel_kernel(float* out, int n){
  int i = blockIdx.x*256 + threadIdx.x;
  if (i < n) out[i] = 12345.0f;
}

// ---------------- atom embedding: h = x @ atom_W + atom_b (fp32) ----------------
__global__ void atom_embed_kernel(const float* __restrict__ x, const float* __restrict__ W,
                                  const float* __restrict__ b, float* __restrict__ h){
  __shared__ float xs[8][FAT];
  int n0 = blockIdx.x * 8;
  int t = threadIdx.x;
  if (t < 8*FAT) xs[t/FAT][t%FAT] = x[(size_t)(n0 + t/FAT)*FAT + t%FAT];
  __syncthreads();
  int c = t;
  float acc[8];
  float bias = b[c];
  #pragma unroll
  for (int r=0;r<8;r++) acc[r]=bias;
  #pragma unroll
  for (int k=0;k<FAT;k++){
    float w = W[k*HDIM + c];
    #pragma unroll
    for (int r=0;r<8;r++) acc[r] += xs[r][k]*w;
  }
  #pragma unroll
  for (int r=0;r<8;r++) h[(size_t)(n0+r)*HDIM + c] = acc[r];
}

// ---------------- CSR build over dst ----------------
__global__ void count_kernel(const int* __restrict__ dst, int* __restrict__ counts, int E){
  int e = blockIdx.x*blockDim.x + threadIdx.x;
  if (e < E) atomicAdd(&counts[dst[e]], 1);
}

__global__ void scan_kernel(const int* __restrict__ counts, int* __restrict__ row_ptr, int n){
  __shared__ int part[1024];
  int t = threadIdx.x;
  int chunk = (n + 1023) >> 10;
  int s = t*chunk, e2 = min(s+chunk, n);
  int sum = 0;
  for (int i=s;i<e2;i++) sum += counts[i];
  part[t] = sum; __syncthreads();
  for (int off=1; off<1024; off<<=1){
    int v = (t>=off) ? part[t-off] : 0;
    __syncthreads();
    part[t] += v;
    __syncthreads();
  }
  int run = part[t]-sum;
  for (int i=s;i<e2;i++){ row_ptr[i]=run; run+=counts[i]; }
  if (e2==n && s<=n) row_ptr[n]=run;
}

__global__ void fill_kernel(const int* __restrict__ dst, int* __restrict__ cursor,
                            int* __restrict__ sorted_eid, int E){
  int e = blockIdx.x*blockDim.x + threadIdx.x;
  if (e < E){ int pos = atomicAdd(&cursor[dst[e]],1); sorted_eid[pos]=e; }
}

__global__ void segstart_kernel(const int* __restrict__ batch, int* __restrict__ segs, int n, int nb){
  int g = blockIdx.x*blockDim.x + threadIdx.x;
  if (g > nb) return;
  int lo=0, hi=n;
  while (lo<hi){ int mid=(lo+hi)>>1; if (batch[mid] < g) lo=mid+1; else hi=mid; }
  segs[g]=lo;
}

// ---------------- GINE message + aggregate (fp32 h -> split-bf16 z) ----------------
__global__ void gine_msg_kernel(const float* __restrict__ h, const float* __restrict__ ea,
                                const float* __restrict__ bW, const float* __restrict__ bb,
                                const int* __restrict__ src, const int* __restrict__ sorted_eid,
                                const int* __restrict__ row_ptr, const float* __restrict__ eps,
                                int layer, short* __restrict__ zh, short* __restrict__ zl){
  __shared__ float wB[FBOND][HDIM];
  __shared__ float bB[HDIM];
  int t = threadIdx.x;
  for (int i=t; i<FBOND*HDIM; i+=256) wB[i/HDIM][i%HDIM] = bW[i];
  if (t < HDIM) bB[t] = bb[t];
  __syncthreads();
  int node = (blockIdx.x*256 + t) >> 6;
  int lane = t & 63;
  if (node >= N_NODES) return;
  int c0 = lane*4;
  float4 hv = *(const float4*)&h[(size_t)node*HDIM + c0];
  float epsf = 1.0f + eps[layer];
  float ax = hv.x*epsf, ay = hv.y*epsf, az = hv.z*epsf, aw = hv.w*epsf;
  int s = row_ptr[node], e = row_ptr[node+1];
  for (int idx=s; idx<e; idx++){
    int eid = sorted_eid[idx];
    int sn  = src[eid];
    float4 hs = *(const float4*)&h[(size_t)sn*HDIM + c0];
    float ex = bB[c0], ey = bB[c0+1], ez = bB[c0+2], ew = bB[c0+3];
    const float* earow = &ea[(size_t)eid*FBOND];
    #pragma unroll
    for (int k=0;k<FBOND;k++){
      float a = earow[k];
      float4 w = *(const float4*)&wB[k][c0];
      ex += a*w.x; ey += a*w.y; ez += a*w.z; ew += a*w.w;
    }
    ax += fmaxf(hs.x+ex, 0.f);
    ay += fmaxf(hs.y+ey, 0.f);
    az += fmaxf(hs.z+ez, 0.f);
    aw += fmaxf(hs.w+ew, 0.f);
  }
  short4 oh, ol;
  oh.x=f2bf(ax); ol.x=f2bf(ax-bf2f(oh.x));
  oh.y=f2bf(ay); ol.y=f2bf(ay-bf2f(oh.y));
  oh.z=f2bf(az); ol.z=f2bf(az-bf2f(oh.z));
  oh.w=f2bf(aw); ol.w=f2bf(aw-bf2f(oh.w));
  *(short4*)&zh[(size_t)node*HDIM + c0] = oh;
  *(short4*)&zl[(size_t)node*HDIM + c0] = ol;
}

// ---------------- pack weights into MFMA B-fragment layout, split hi/lo -------------
__global__ void packB_kernel(const float* __restrict__ B, short* __restrict__ Bph,
                             short* __restrict__ Bpl, int K, int N){
  int idx = blockIdx.x*256 + threadIdx.x;
  if (idx >= K*N) return;
  int b    = idx & 7;
  int lane = (idx >> 3) & 63;
  int t2   = idx >> 9;
  int KT   = K >> 5;
  int kt   = t2 % KT, nt = t2 / KT;
  int k = kt*32 + ((lane>>4)<<3) + b;
  int n = nt*16 + (lane&15);
  float w = B[(size_t)k*N + n];
  short hi = f2bf(w);
  Bph[idx] = hi;
  Bpl[idx] = f2bf(w - bf2f(hi));
}

// ---------------- split-bf16 MFMA GEMM over row range [mBase, mEnd) ----------------
// acc += ah*bh + ah*bl + al*bh  (fp32-grade)
// A rows indexed relative to aBase; EPI1 C rows relative to cBase (chunked c1).
// EPI 1: v = relu(acc*sc+sh)          -> write split (Chi, Clo) at (row-cBase)
// EPI 2: v = relu(acc*sc+sh) + residf -> write fp32 Cf at absolute row
template<int EPI>
__launch_bounds__(256)
__global__ void gemm_mfma(const short* __restrict__ Ah, const short* __restrict__ Al,
                          const short* __restrict__ Bh, const short* __restrict__ Bl,
                          int mBase, int mEnd, int N, int K,
                          const float* __restrict__ sc, const float* __restrict__ sh,
                          short* __restrict__ Chi, short* __restrict__ Clo,
                          float* __restrict__ Cf, const float* __restrict__ residf,
                          int aBase, int cBase){
  int lane = threadIdx.x & 63;
  int wid  = threadIdx.x >> 6;
  int m0 = mBase + blockIdx.y * 64;
  int n0 = blockIdx.x * 128 + wid * 32;
  int lrow = lane & 15;
  int lk8  = (lane >> 4) << 3;
  int KT = K >> 5;

  f32x4 acc[4][2];
  #pragma unroll
  for (int i=0;i<4;i++)
    #pragma unroll
    for (int j=0;j<2;j++) acc[i][j] = (f32x4){0.f,0.f,0.f,0.f};

  size_t aoff[4];
  #pragma unroll
  for (int mf=0; mf<4; mf++){
    int r = m0 + mf*16 + lrow;
    if (r >= mEnd) r = mEnd-1;    // clamp: OOB A rows only feed OOB D rows (unstored)
    aoff[mf] = (size_t)(r - aBase)*K + lk8;
  }
  size_t boff = ((size_t)(n0 >> 4) * KT) * 512 + lane*8;

  for (int kt=0; kt<KT; kt++){
    s8v ah[4], al[4];
    #pragma unroll
    for (int mf=0; mf<4; mf++){
      ah[mf] = *(const s8v*)(Ah + aoff[mf] + kt*32);
      al[mf] = *(const s8v*)(Al + aoff[mf] + kt*32);
    }
    s8v bh[2], bl[2];
    bh[0] = *(const s8v*)(Bh + boff + (size_t)kt*512);
    bl[0] = *(const s8v*)(Bl + boff + (size_t)kt*512);
    bh[1] = *(const s8v*)(Bh + boff + (size_t)(KT + kt)*512);
    bl[1] = *(const s8v*)(Bl + boff + (size_t)(KT + kt)*512);
    #pragma unroll
    for (int nf=0; nf<2; nf++){
      #pragma unroll
      for (int mf=0; mf<4; mf++){
        acc[mf][nf] = __builtin_amdgcn_mfma_f32_16x16x32_bf16(ah[mf], bh[nf], acc[mf][nf], 0,0,0);
        acc[mf][nf] = __builtin_amdgcn_mfma_f32_16x16x32_bf16(ah[mf], bl[nf], acc[mf][nf], 0,0,0);
        acc[mf][nf] = __builtin_amdgcn_mfma_f32_16x16x32_bf16(al[mf], bh[nf], acc[mf][nf], 0,0,0);
      }
    }
  }

  int drow0 = (lane >> 4) * 4;
  #pragma unroll
  for (int nf=0; nf<2; nf++){
    int col = n0 + nf*16 + lrow;
    float scv = sc[col], shv = sh[col];
    #pragma unroll
    for (int mf=0; mf<4; mf++){
      #pragma unroll
      for (int r=0; r<4; r++){
        int row = m0 + mf*16 + drow0 + r;
        if (row >= mEnd) continue;
        float v = fmaxf(acc[mf][nf][r]*scv + shv, 0.f);
        if (EPI == 1){
          short hi = f2bf(v);
          Chi[(size_t)(row-cBase)*N + col] = hi;
          Clo[(size_t)(row-cBase)*N + col] = f2bf(v - bf2f(hi));
        } else {
          v += residf[(size_t)row*N + col];
          Cf[(size_t)row*N + col] = v;
        }
      }
    }
  }
}

// ---------------- fp32 tiled GEMM (LSTM gates): C = A@B + bias ----------------
__launch_bounds__(256)
__global__ void gemm_f32(const float* __restrict__ A, const float* __restrict__ B,
                         float* __restrict__ C, int M, int N, int K,
                         const float* __restrict__ bias){
  __shared__ float As[32*132];
  __shared__ float Bs[32*68];
  int t  = threadIdx.x;
  int tx = t & 15, ty = t >> 4;
  int row0 = blockIdx.y*128, col0 = blockIdx.x*64;
  float acc[8][4];
  #pragma unroll
  for (int i=0;i<8;i++)
    #pragma unroll
    for (int j=0;j<4;j++) acc[i][j]=0.f;

  int r0 = t >> 2, fq = t & 3;
  int bk = t >> 4, cq = t & 15;

  for (int kt=0; kt<K; kt+=32){
    #pragma unroll
    for (int half=0; half<2; half++){
      int row = r0 + half*64;
      int grow = row0 + row;
      #pragma unroll
      for (int fo=0; fo<2; fo++){
        int kk = (fq + fo*4)*4;
        float4 a4 = make_float4(0.f,0.f,0.f,0.f);
        if (grow < M) a4 = *(const float4*)&A[(size_t)grow*K + kt + kk];
        As[(kk+0)*132 + row] = a4.x;
        As[(kk+1)*132 + row] = a4.y;
        As[(kk+2)*132 + row] = a4.z;
        As[(kk+3)*132 + row] = a4.w;
      }
    }
    #pragma unroll
    for (int half=0; half<2; half++){
      int kk = bk + half*16;
      float4 b4 = *(const float4*)&B[(size_t)(kt+kk)*N + col0 + cq*4];
      *(float4*)&Bs[kk*68 + cq*4] = b4;
    }
    __syncthreads();
    #pragma unroll 8
    for (int k=0;k<32;k++){
      float4 a0 = *(const float4*)&As[k*132 + ty*8];
      float4 a1 = *(const float4*)&As[k*132 + ty*8 + 4];
      float4 b  = *(const float4*)&Bs[k*68 + tx*4];
      float av[8] = {a0.x,a0.y,a0.z,a0.w,a1.x,a1.y,a1.z,a1.w};
      float bv[4] = {b.x,b.y,b.z,b.w};
      #pragma unroll
      for (int i=0;i<8;i++)
        #pragma unroll
        for (int j=0;j<4;j++) acc[i][j] += av[i]*bv[j];
    }
    __syncthreads();
  }

  int cc0 = col0 + tx*4;
  float4 shv = *(const float4*)&bias[cc0];
  #pragma unroll
  for (int i=0;i<8;i++){
    int rr = row0 + ty*8 + i;
    if (rr >= M) break;
    float4 v = make_float4(acc[i][0]+shv.x, acc[i][1]+shv.y, acc[i][2]+shv.z, acc[i][3]+shv.w);
    *(float4*)&C[(size_t)rr*N + cc0] = v;
  }
}

// ---------------- weight prep ----------------
__global__ void wcat_kernel(const float* __restrict__ Wih, const float* __restrict__ Whh,
                            const float* __restrict__ bih, const float* __restrict__ bhh,
                            float* __restrict__ Wcat, float* __restrict__ bias_c){
  int idx = blockIdx.x*256 + threadIdx.x;
  if (idx < 768*1024){
    int k = idx >> 10, n = idx & 1023;
    Wcat[idx] = (k < 512) ? Wih[(size_t)n*512 + k] : Whh[(size_t)n*256 + (k-512)];
  }
  if (idx < 1024) bias_c[idx] = bih[idx] + bhh[idx];
}

__global__ void fold_kernel(
  const float* __restrict__ b1,  const float* __restrict__ g1,  const float* __restrict__ bb1,
  const float* __restrict__ m1,  const float* __restrict__ v1,
  const float* __restrict__ b2,  const float* __restrict__ g2,  const float* __restrict__ bb2,
  const float* __restrict__ m2,  const float* __restrict__ v2,
  const float* __restrict__ cb1, const float* __restrict__ cg1, const float* __restrict__ cbb1,
  const float* __restrict__ cm1, const float* __restrict__ cv1,
  const float* __restrict__ cb2, const float* __restrict__ cg2, const float* __restrict__ cbb2,
  const float* __restrict__ cm2, const float* __restrict__ cv2,
  float* __restrict__ sc1, float* __restrict__ sh1,
  float* __restrict__ sc2, float* __restrict__ sh2,
  float* __restrict__ csc1, float* __restrict__ csh1,
  float* __restrict__ csc2, float* __restrict__ csh2){
  int idx = blockIdx.x*256 + threadIdx.x;
  const int n1 = NLAY*512, n2 = NLAY*256;
  if (idx < n1){
    float s = g1[idx]*rsqrtf(v1[idx]+1e-5f);
    sc1[idx]=s; sh1[idx]=(b1[idx]-m1[idx])*s + bb1[idx];
  } else if (idx < n1+n2){
    int i = idx-n1;
    float s = g2[i]*rsqrtf(v2[i]+1e-5f);
    sc2[i]=s; sh2[i]=(b2[i]-m2[i])*s + bb2[i];
  } else if (idx < n1+n2+256){
    int i = idx-n1-n2;
    float s = cg1[i]*rsqrtf(cv1[i]+1e-5f);
    csc1[i]=s; csh1[i]=(cb1[i]-cm1[i])*s + cbb1[i];
  } else if (idx < n1+n2+256+128){
    int i = idx-n1-n2-256;
    float s = cg2[i]*rsqrtf(cv2[i]+1e-5f);
    csc2[i]=s; csh2[i]=(cb2[i]-cm2[i])*s + cbb2[i];
  }
}

// ---------------- LSTM pointwise ----------------
__global__ void lstm_kernel(const float* __restrict__ gates, float* __restrict__ cst,
                            float* __restrict__ qs){
  int idx = blockIdx.x*256 + threadIdx.x;
  int b = idx >> 8, j = idx & 255;
  const float* g = &gates[(size_t)b*1024];
  float ig = sigmoidf_(g[j]);
  float fg = sigmoidf_(g[j+256]);
  float gg = tanhf(g[j+512]);
  float og = sigmoidf_(g[j+768]);
  float c  = fg*cst[idx] + ig*gg;
  float hv = og*tanhf(c);
  cst[idx] = c;
  qs[(size_t)b*768 + j]       = hv;
  qs[(size_t)b*768 + 512 + j] = hv;
}

// ---------------- attention energy: ener[n] = dot(h[n], hst[batch[n]]) ----------------
__global__ void ener_kernel(const float* __restrict__ h, const float* __restrict__ qs,
                            const int* __restrict__ batch, float* __restrict__ ener){
  int node = (blockIdx.x*256 + threadIdx.x) >> 6;
  int lane = threadIdx.x & 63;
  if (node >= N_NODES) return;
  int b = batch[node];
  float4 hv = *(const float4*)&h[(size_t)node*HDIM + lane*4];
  float4 qv = *(const float4*)&qs[(size_t)b*768 + 512 + lane*4];
  float v = hv.x*qv.x + hv.y*qv.y + hv.z*qv.z + hv.w*qv.w;
  for (int off=32; off; off>>=1) v += __shfl_down(v, off);
  if (lane==0) ener[node] = v;
}

// ---------------- segment softmax + weighted sum r ----------------
__global__ void attn_r_kernel(const float* __restrict__ h, const float* __restrict__ ener,
                              const int* __restrict__ segs, float* __restrict__ qs){
  __shared__ float red[256];
  int g = blockIdx.x, t = threadIdx.x;
  int s = segs[g], e = segs[g+1];
  float m = -INFINITY;
  for (int i=s+t; i<e; i+=256) m = fmaxf(m, ener[i]);
  red[t]=m; __syncthreads();
  for (int o=128;o>0;o>>=1){ if (t<o) red[t]=fmaxf(red[t],red[t+o]); __syncthreads(); }
  m = red[0];
  float msel = (e > s) ? m : 0.0f;
  __syncthreads();
  float a = 0.f;
  for (int i=s+t; i<e; i+=256) a += expf(ener[i]-msel);
  red[t]=a; __syncthreads();
  for (int o=128;o>0;o>>=1){ if (t<o) red[t]+=red[t+o]; __syncthreads(); }
  float inv = 1.0f/(red[0] + 1e-16f);
  float racc = 0.f;
  for (int i=s;i<e;i++) racc += expf(ener[i]-msel) * h[(size_t)i*HDIM + t];
  qs[(size_t)g*768 + 256 + t] = racc*inv;
}

// ---------------- fused classifier ----------------
__global__ void classifier_kernel(const float* __restrict__ qs,
   const float* __restrict__ cW1, const float* __restrict__ csc1, const float* __restrict__ csh1,
   const float* __restrict__ cW2, const float* __restrict__ csc2, const float* __restrict__ csh2,
   const float* __restrict__ cW3, const float* __restrict__ cb3, float* __restrict__ out){
  __shared__ float sq[512];
  __shared__ float so1[256];
  __shared__ float so2[128];
  __shared__ float fr[256];
  int g = blockIdx.x, t = threadIdx.x;
  sq[t]     = qs[(size_t)g*768 + t];
  sq[t+256] = qs[(size_t)g*768 + 256 + t];
  __syncthreads();
  float acc = 0.f;
  for (int k=0;k<512;k++) acc += sq[k]*cW1[(size_t)k*256 + t];
  so1[t] = fmaxf(acc*csc1[t]+csh1[t], 0.f);
  __syncthreads();
  if (t < 128){
    float a2 = 0.f;
    for (int k=0;k<256;k++) a2 += so1[k]*cW2[(size_t)k*128 + t];
    so2[t] = fmaxf(a2*csc2[t]+csh2[t], 0.f);
  }
  __syncthreads();
  fr[t] = (t<128) ? so2[t]*cW3[t] : 0.f;
  __syncthreads();
  for (int o=128;o>0;o>>=1){ if (t<o) fr[t]+=fr[t+o]; __syncthreads(); }
  if (t==0) out[g] = fr[0] + cb3[0];
}

// ---------------- host ----------------
extern "C" void kernel_launch(void* const* d_in, const int* in_sizes, int n_in,
                              void* d_out, int out_size, void* d_ws, size_t ws_size,
                              hipStream_t stream){
  const float* x         = (const float*)d_in[0];
  const float* edge_attr = (const float*)d_in[1];
  const int*   edge_idx  = (const int*)  d_in[2];
  const int*   batch     = (const int*)  d_in[3];
  const float* atom_W    = (const float*)d_in[4];
  const float* atom_b    = (const float*)d_in[5];
  const float* bond_W    = (const float*)d_in[6];
  const float* bond_b    = (const float*)d_in[7];
  const float* eps       = (const float*)d_in[8];
  const float* W1        = (const float*)d_in[9];
  const float* b1        = (const float*)d_in[10];
  const float* bn1_g     = (const float*)d_in[11];
  const float* bn1_b     = (const float*)d_in[12];
  const float* bn1_m     = (const float*)d_in[13];
  const float* bn1_v     = (const float*)d_in[14];
  const float* W2        = (const float*)d_in[15];
  const float* b2        = (const float*)d_in[16];
  const float* bn_g      = (const float*)d_in[17];
  const float* bn_b      = (const float*)d_in[18];
  const float* bn_m      = (const float*)d_in[19];
  const float* bn_v      = (const float*)d_in[20];
  const float* lstm_Wih  = (const float*)d_in[21];
  const float* lstm_Whh  = (const float*)d_in[22];
  const float* lstm_bih  = (const float*)d_in[23];
  const float* lstm_bhh  = (const float*)d_in[24];
  const float* cW1       = (const float*)d_in[25];
  const float* cb1       = (const float*)d_in[26];
  const float* cbn1_g    = (const float*)d_in[27];
  const float* cbn1_b    = (const float*)d_in[28];
  const float* cbn1_m    = (const float*)d_in[29];
  const float* cbn1_v    = (const float*)d_in[30];
  const float* cW2       = (const float*)d_in[31];
  const float* cb2       = (const float*)d_in[32];
  const float* cbn2_g    = (const float*)d_in[33];
  const float* cbn2_b    = (const float*)d_in[34];
  const float* cbn2_m    = (const float*)d_in[35];
  const float* cbn2_v    = (const float*)d_in[36];
  const float* cW3       = (const float*)d_in[37];
  const float* cb3       = (const float*)d_in[38];

  const int* src = edge_idx;
  const int* dst = edge_idx + N_EDGES;

  char* ws = (char*)d_ws;
  size_t off = 0;
  auto alloc = [&](size_t bytes)->void*{
    void* p = ws + off; off += (bytes + 255) & ~(size_t)255; return p;
  };
  float* h       = (float*)alloc((size_t)N_NODES*HDIM*4);     // 102.4 MB fp32 master
  short* zh      = (short*)alloc((size_t)N_NODES*HDIM*2);     //  51.2 MB
  short* zl      = (short*)alloc((size_t)N_NODES*HDIM*2);     //  51.2 MB
  int*   row_ptr = (int*)  alloc((size_t)(N_NODES+1)*4);
  int*   cursor  = (int*)  alloc((size_t)N_NODES*4);
  int*   s_eid   = (int*)  alloc((size_t)N_EDGES*4);
  int*   segs    = (int*)  alloc((size_t)(NB+1)*4);
  short* W1ph    = (short*)alloc((size_t)NLAY*HDIM*2*HDIM*2);
  short* W1pl    = (short*)alloc((size_t)NLAY*HDIM*2*HDIM*2);
  short* W2ph    = (short*)alloc((size_t)NLAY*HDIM*2*HDIM*2);
  short* W2pl    = (short*)alloc((size_t)NLAY*HDIM*2*HDIM*2);
  float* sc1     = (float*)alloc(NLAY*512*4);
  float* sh1     = (float*)alloc(NLAY*512*4);
  float* sc2     = (float*)alloc(NLAY*256*4);
  float* sh2     = (float*)alloc(NLAY*256*4);
  float* csc1    = (float*)alloc(256*4);
  float* csh1    = (float*)alloc(256*4);
  float* csc2    = (float*)alloc(128*4);
  float* csh2    = (float*)alloc(128*4);

  // ---- adaptive c1 chunk (split pair) from remaining workspace ----
  if (off >= ws_size){
    sentinel_kernel<<<(out_size+255)/256, 256, 0, stream>>>((float*)d_out, out_size);
    return;
  }
  size_t remain = ws_size - off;
  size_t chMax  = remain / (2*HDIM*2*2);           // bytes per row: 512 cols * 2 arrays * 2B
  int CH = (int)((chMax/64)*64);
  if (CH < 64){
    sentinel_kernel<<<(out_size+255)/256, 256, 0, stream>>>((float*)d_out, out_size);
    return;
  }
  if (CH > 100032) CH = 100032;
  short* c1h = (short*)alloc((size_t)CH*2*HDIM*2);
  short* c1l = (short*)alloc((size_t)CH*2*HDIM*2);

  // Set2Set scratch aliases zh (dead after last GEMM1); ener aliases zl.
  char*  zb      = (char*)(void*)zh;
  float* gates   = (float*)zb;                          // 16.78 MB
  float* qs      = (float*)(zb + 16777216);             // 12.58 MB
  float* cst     = (float*)(zb + 29360128);             //  4.19 MB
  float* Wcat    = (float*)(zb + 33554432);             //  3.15 MB
  float* bias_c  = (float*)(zb + 36700160);             //  4 KB
  float* ener    = (float*)(void*)zl;

  // ---- prep: fold BN+bias, pack weights (split hi/lo) ----
  fold_kernel<<<(NLAY*512+NLAY*256+256+128+255)/256, 256, 0, stream>>>(
      b1, bn1_g, bn1_b, bn1_m, bn1_v,
      b2, bn_g,  bn_b,  bn_m,  bn_v,
      cb1, cbn1_g, cbn1_b, cbn1_m, cbn1_v,
      cb2, cbn2_g, cbn2_b, cbn2_m, cbn2_v,
      sc1, sh1, sc2, sh2, csc1, csh1, csc2, csh2);
  for (int l=0; l<NLAY; l++){
    packB_kernel<<<(HDIM*2*HDIM)/256, 256, 0, stream>>>(
        W1 + (size_t)l*HDIM*2*HDIM, W1ph + (size_t)l*HDIM*2*HDIM, W1pl + (size_t)l*HDIM*2*HDIM, HDIM, 2*HDIM);
    packB_kernel<<<(HDIM*2*HDIM)/256, 256, 0, stream>>>(
        W2 + (size_t)l*HDIM*2*HDIM, W2ph + (size_t)l*HDIM*2*HDIM, W2pl + (size_t)l*HDIM*2*HDIM, 2*HDIM, HDIM);
  }

  // ---- embeddings ----
  atom_embed_kernel<<<N_NODES/8, 256, 0, stream>>>(x, atom_W, atom_b, h);

  // ---- CSR by dst + batch segment starts ----
  hipMemsetAsync(cursor, 0, (size_t)N_NODES*4, stream);
  count_kernel<<<(N_EDGES+255)/256, 256, 0, stream>>>(dst, cursor, N_EDGES);
  scan_kernel<<<1, 1024, 0, stream>>>(cursor, row_ptr, N_NODES);
  hipMemcpyAsync(cursor, row_ptr, (size_t)N_NODES*4, hipMemcpyDeviceToDevice, stream);
  fill_kernel<<<(N_EDGES+255)/256, 256, 0, stream>>>(dst, cursor, s_eid, N_EDGES);
  segstart_kernel<<<(NB+256)/256, 256, 0, stream>>>(batch, segs, N_NODES, NB);

  // ---- GINE layers (c1 chunked through the adaptive buffer) ----
  for (int l=0; l<NLAY; l++){
    gine_msg_kernel<<<N_NODES/4, 256, 0, stream>>>(h, edge_attr, bond_W, bond_b,
                                                   src, s_eid, row_ptr, eps, l, zh, zl);
    for (int m0=0; m0<N_NODES; m0+=CH){
      int mEnd = min(N_NODES, m0+CH);
      int gyc  = (mEnd-m0+63)/64;
      gemm_mfma<1><<<dim3(4, gyc), 256, 0, stream>>>(
          zh, zl, W1ph + (size_t)l*HDIM*2*HDIM, W1pl + (size_t)l*HDIM*2*HDIM,
          m0, mEnd, 2*HDIM, HDIM, sc1 + l*512, sh1 + l*512,
          c1h, c1l, nullptr, nullptr, 0, m0);
      gemm_mfma<2><<<dim3(2, gyc), 256, 0, stream>>>(
          c1h, c1l, W2ph + (size_t)l*HDIM*2*HDIM, W2pl + (size_t)l*HDIM*2*HDIM,
          m0, mEnd, HDIM, 2*HDIM, sc2 + l*256, sh2 + l*256,
          nullptr, nullptr, h, h, m0, 0);
    }
  }

  // ---- Set2Set (scratch aliases zh/zl, now dead) ----
  wcat_kernel<<<(768*1024+255)/256, 256, 0, stream>>>(lstm_Wih, lstm_Whh, lstm_bih, lstm_bhh, Wcat, bias_c);
  hipMemsetAsync(qs,  0, (size_t)NB*768*4, stream);
  hipMemsetAsync(cst, 0, (size_t)NB*HDIM*4, stream);
  for (int sstep=0; sstep<3; sstep++){
    gemm_f32<<<dim3(1024/64, NB/128), 256, 0, stream>>>(qs, Wcat, gates, NB, 1024, 768, bias_c);
    lstm_kernel<<<(NB*HDIM)/256, 256, 0, stream>>>(gates, cst, qs);
    ener_kernel<<<N_NODES/4, 256, 0, stream>>>(h, qs, batch, ener);
    attn_r_kernel<<<NB, 256, 0, stream>>>(h, ener, segs, qs);
  }

  // ---- classifier ----
  classifier_kernel<<<NB, 256, 0, stream>>>(qs, cW1, csc1, csh1, cW2, csc2, csh2,
                                            cW3, cb3, (float*)d_out);
}

// Round 6
// 3356.498 us; speedup vs baseline: 1.4310x; 1.4310x over previous
//
#include <hip/hip_runtime.h>
#include <hip/hip_bf16.h>

#define N_NODES 100000
#define N_EDGES 400000
#define NB      4096
#define FAT     30
#define FBOND   11
#define HDIM    256
#define NLAY    5

typedef short s8v  __attribute__((ext_vector_type(8)));
typedef float f32x4 __attribute__((ext_vector_type(4)));

static __device__ __forceinline__ float sigmoidf_(float x){ return 1.0f/(1.0f+expf(-x)); }
static __device__ __forceinline__ float bf2f(short s){
  return __uint_as_float(((unsigned)(unsigned short)s) << 16);
}
static __device__ __forceinline__ short f2bf(float f){   // RNE
  unsigned u = __float_as_uint(f);
  u += 0x7fffu + ((u >> 16) & 1u);
  return (short)(u >> 16);
}

// ---------------- sentinel (ws too small diagnostic) ----------------
__global__ void sentinel_kernel(float* out, int n){
  int i = blockIdx.x*256 + threadIdx.x;
  if (i < n) out[i] = 12345.0f;
}

// ---------------- atom embedding: h = x @ atom_W + atom_b (fp32) ----------------
__global__ void atom_embed_kernel(const float* __restrict__ x, const float* __restrict__ W,
                                  const float* __restrict__ b, float* __restrict__ h){
  __shared__ float xs[8][FAT];
  int n0 = blockIdx.x * 8;
  int t = threadIdx.x;
  if (t < 8*FAT) xs[t/FAT][t%FAT] = x[(size_t)(n0 + t/FAT)*FAT + t%FAT];
  __syncthreads();
  int c = t;
  float acc[8];
  float bias = b[c];
  #pragma unroll
  for (int r=0;r<8;r++) acc[r]=bias;
  #pragma unroll
  for (int k=0;k<FAT;k++){
    float w = W[k*HDIM + c];
    #pragma unroll
    for (int r=0;r<8;r++) acc[r] += xs[r][k]*w;
  }
  #pragma unroll
  for (int r=0;r<8;r++) h[(size_t)(n0+r)*HDIM + c] = acc[r];
}

// ---------------- CSR build over dst ----------------
__global__ void count_kernel(const int* __restrict__ dst, int* __restrict__ counts, int E){
  int e = blockIdx.x*blockDim.x + threadIdx.x;
  if (e < E) atomicAdd(&counts[dst[e]], 1);
}

__global__ void scan_kernel(const int* __restrict__ counts, int* __restrict__ row_ptr, int n){
  __shared__ int part[1024];
  int t = threadIdx.x;
  int chunk = (n + 1023) >> 10;
  int s = t*chunk, e2 = min(s+chunk, n);
  int sum = 0;
  for (int i=s;i<e2;i++) sum += counts[i];
  part[t] = sum; __syncthreads();
  for (int off=1; off<1024; off<<=1){
    int v = (t>=off) ? part[t-off] : 0;
    __syncthreads();
    part[t] += v;
    __syncthreads();
  }
  int run = part[t]-sum;
  for (int i=s;i<e2;i++){ row_ptr[i]=run; run+=counts[i]; }
  if (e2==n && s<=n) row_ptr[n]=run;
}

__global__ void fill_kernel(const int* __restrict__ dst, int* __restrict__ cursor,
                            int* __restrict__ sorted_eid, int E){
  int e = blockIdx.x*blockDim.x + threadIdx.x;
  if (e < E){ int pos = atomicAdd(&cursor[dst[e]],1); sorted_eid[pos]=e; }
}

__global__ void segstart_kernel(const int* __restrict__ batch, int* __restrict__ segs, int n, int nb){
  int g = blockIdx.x*blockDim.x + threadIdx.x;
  if (g > nb) return;
  int lo=0, hi=n;
  while (lo<hi){ int mid=(lo+hi)>>1; if (batch[mid] < g) lo=mid+1; else hi=mid; }
  segs[g]=lo;
}

// ---------------- one-time edge reorder: linear src + edge_attr in CSR order -------
__global__ void reorder_kernel(const int* __restrict__ s_eid, const int* __restrict__ src,
                               const float* __restrict__ ea,
                               int* __restrict__ s_src, float* __restrict__ ea_r, int E){
  int i = blockIdx.x*256 + threadIdx.x;
  if (i >= E) return;
  int eid = s_eid[i];
  s_src[i] = src[eid];
  const float* a = ea + (size_t)eid*FBOND;
  float* o = ea_r + (size_t)i*FBOND;
  #pragma unroll
  for (int k=0;k<FBOND;k++) o[k] = a[k];
}

// ---------------- GINE message + aggregate (fp32 h -> split-bf16 z) ----------------
template<bool RE>
__global__ void gine_msg_kernel(const float* __restrict__ h, const float* __restrict__ ea,
                                const float* __restrict__ bW, const float* __restrict__ bb,
                                const int* __restrict__ src, const int* __restrict__ s_eid,
                                const int* __restrict__ s_src, const float* __restrict__ ea_r,
                                const int* __restrict__ row_ptr, const float* __restrict__ eps,
                                int layer, short* __restrict__ zh, short* __restrict__ zl){
  __shared__ float wB[FBOND][HDIM];
  __shared__ float bB[HDIM];
  int t = threadIdx.x;
  for (int i=t; i<FBOND*HDIM; i+=256) wB[i/HDIM][i%HDIM] = bW[i];
  if (t < HDIM) bB[t] = bb[t];
  __syncthreads();
  int node = (blockIdx.x*256 + t) >> 6;
  int lane = t & 63;
  if (node >= N_NODES) return;
  int c0 = lane*4;
  float4 hv = *(const float4*)&h[(size_t)node*HDIM + c0];
  float epsf = 1.0f + eps[layer];
  float ax = hv.x*epsf, ay = hv.y*epsf, az = hv.z*epsf, aw = hv.w*epsf;
  int s = row_ptr[node], e = row_ptr[node+1];
  for (int idx=s; idx<e; idx++){
    int sn; const float* earow;
    if (RE){ sn = s_src[idx];                 earow = ea_r + (size_t)idx*FBOND; }
    else   { int eid = s_eid[idx]; sn = src[eid]; earow = ea + (size_t)eid*FBOND; }
    float4 hs = *(const float4*)&h[(size_t)sn*HDIM + c0];
    float ex = bB[c0], ey = bB[c0+1], ez = bB[c0+2], ew = bB[c0+3];
    #pragma unroll
    for (int k=0;k<FBOND;k++){
      float a = earow[k];
      float4 w = *(const float4*)&wB[k][c0];
      ex += a*w.x; ey += a*w.y; ez += a*w.z; ew += a*w.w;
    }
    ax += fmaxf(hs.x+ex, 0.f);
    ay += fmaxf(hs.y+ey, 0.f);
    az += fmaxf(hs.z+ez, 0.f);
    aw += fmaxf(hs.w+ew, 0.f);
  }
  short4 oh, ol;
  oh.x=f2bf(ax); ol.x=f2bf(ax-bf2f(oh.x));
  oh.y=f2bf(ay); ol.y=f2bf(ay-bf2f(oh.y));
  oh.z=f2bf(az); ol.z=f2bf(az-bf2f(oh.z));
  oh.w=f2bf(aw); ol.w=f2bf(aw-bf2f(oh.w));
  *(short4*)&zh[(size_t)node*HDIM + c0] = oh;
  *(short4*)&zl[(size_t)node*HDIM + c0] = ol;
}

// ---------------- pack weights into MFMA B-fragment layout, split hi/lo -------------
__global__ void packB_kernel(const float* __restrict__ B, short* __restrict__ Bph,
                             short* __restrict__ Bpl, int K, int N){
  int idx = blockIdx.x*256 + threadIdx.x;
  if (idx >= K*N) return;
  int b    = idx & 7;
  int lane = (idx >> 3) & 63;
  int t2   = idx >> 9;
  int KT   = K >> 5;
  int kt   = t2 % KT, nt = t2 / KT;
  int k = kt*32 + ((lane>>4)<<3) + b;
  int n = nt*16 + (lane&15);
  float w = B[(size_t)k*N + n];
  short hi = f2bf(w);
  Bph[idx] = hi;
  Bpl[idx] = f2bf(w - bf2f(hi));
}

// ---------------- pack LSTM [Wih|Whh]^T (K=768, N=1024) + bias, split hi/lo --------
__global__ void packWcat_kernel(const float* __restrict__ Wih, const float* __restrict__ Whh,
                                const float* __restrict__ bih, const float* __restrict__ bhh,
                                short* __restrict__ Wch, short* __restrict__ Wcl,
                                float* __restrict__ bias_c){
  int idx = blockIdx.x*256 + threadIdx.x;
  if (idx < 1024) bias_c[idx] = bih[idx] + bhh[idx];
  if (idx >= 768*1024) return;
  int b    = idx & 7;
  int lane = (idx >> 3) & 63;
  int t2   = idx >> 9;
  const int KT = 24;
  int kt   = t2 % KT, nt = t2 / KT;
  int k = kt*32 + ((lane>>4)<<3) + b;
  int n = nt*16 + (lane&15);
  float w = (k < 512) ? Wih[(size_t)n*512 + k] : Whh[(size_t)n*256 + (k-512)];
  short hi = f2bf(w);
  Wch[idx] = hi;
  Wcl[idx] = f2bf(w - bf2f(hi));
}

// ---------------- split q_star||hst into bf16 hi/lo ----------------
__global__ void qs_pack_kernel(const float* __restrict__ qs, short* __restrict__ qsh,
                               short* __restrict__ qsl){
  int idx = blockIdx.x*256 + threadIdx.x;   // NB*768
  float v = qs[idx];
  short hi = f2bf(v);
  qsh[idx] = hi;
  qsl[idx] = f2bf(v - bf2f(hi));
}

// ---------------- split-bf16 MFMA GEMM, LDS-staged A, double-buffered --------------
// acc += ah*bh + ah*bl + al*bh  (fp32-grade). K multiple of 64.
// block: 4 waves, tile 64(M) x 128(N); wave tile 64x32.
// EPI 0: Cf = acc + sh[col]                     (bias only, fp32 out)
// EPI 1: v = relu(acc*sc+sh) -> split (Chi,Clo) at row-cBase
// EPI 2: v = relu(acc*sc+sh) + residf -> fp32 Cf at absolute row
template<int EPI>
__launch_bounds__(256)
__global__ void gemm_mfma(const short* __restrict__ Ah, const short* __restrict__ Al,
                          const short* __restrict__ Bh, const short* __restrict__ Bl,
                          int mBase, int mEnd, int N, int K,
                          const float* __restrict__ sc, const float* __restrict__ sh,
                          short* __restrict__ Chi, short* __restrict__ Clo,
                          float* __restrict__ Cf, const float* __restrict__ residf,
                          int aBase, int cBase){
  __shared__ short As[2][2][64*72];   // [dbuf][hi/lo][row*72 + k], row stride 144B
  int t    = threadIdx.x;
  int lane = t & 63;
  int wid  = t >> 6;
  int m0 = mBase + blockIdx.y * 64;
  int n0 = blockIdx.x * 128 + wid * 32;
  int lrow = lane & 15;
  int lk8  = (lane >> 4) << 3;
  int KT = K >> 5;
  int NT = K >> 6;

  f32x4 acc[4][2];
  #pragma unroll
  for (int i=0;i<4;i++)
    #pragma unroll
    for (int j=0;j<2;j++) acc[i][j] = (f32x4){0.f,0.f,0.f,0.f};

  // staging: 2 chunks/thread, rows r0=t>>3 (0..31) and r0+32, 16B chunk c8=t&7
  int r0 = t >> 3, c8 = t & 7;
  int gr0 = min(m0 + r0,      mEnd-1) - aBase;
  int gr1 = min(m0 + r0 + 32, mEnd-1) - aBase;
  const short* pa0h = Ah + (size_t)gr0*K + c8*8;
  const short* pa0l = Al + (size_t)gr0*K + c8*8;
  const short* pa1h = Ah + (size_t)gr1*K + c8*8;
  const short* pa1l = Al + (size_t)gr1*K + c8*8;
  int wsh0 = r0*72 + c8*8;
  int wsh1 = (r0+32)*72 + c8*8;

  size_t boff = ((size_t)(n0 >> 4) * KT) * 512 + lane*8;

  // prologue: stage 0
  s8v vh0 = *(const s8v*)(pa0h);
  s8v vh1 = *(const s8v*)(pa1h);
  s8v vl0 = *(const s8v*)(pa0l);
  s8v vl1 = *(const s8v*)(pa1l);
  *(s8v*)&As[0][0][wsh0] = vh0;  *(s8v*)&As[0][0][wsh1] = vh1;
  *(s8v*)&As[0][1][wsh0] = vl0;  *(s8v*)&As[0][1][wsh1] = vl1;
  __syncthreads();

  for (int st=0; st<NT; ++st){
    int cur = st & 1;
    if (st+1 < NT){                       // issue next-stage loads early (hide under MFMA)
      int ko = (st+1)*64;
      vh0 = *(const s8v*)(pa0h + ko);
      vh1 = *(const s8v*)(pa1h + ko);
      vl0 = *(const s8v*)(pa0l + ko);
      vl1 = *(const s8v*)(pa1l + ko);
    }
    #pragma unroll
    for (int ktl=0; ktl<2; ++ktl){
      int kt = st*2 + ktl;
      s8v bh0 = *(const s8v*)(Bh + boff + (size_t)kt*512);
      s8v bl0 = *(const s8v*)(Bl + boff + (size_t)kt*512);
      s8v bh1 = *(const s8v*)(Bh + boff + (size_t)(KT + kt)*512);
      s8v bl1 = *(const s8v*)(Bl + boff + (size_t)(KT + kt)*512);
      int ksh = ktl*32 + lk8;
      #pragma unroll
      for (int mf=0; mf<4; ++mf){
        int rsh = (mf*16 + lrow)*72 + ksh;
        s8v ah = *(const s8v*)&As[cur][0][rsh];
        s8v al = *(const s8v*)&As[cur][1][rsh];
        acc[mf][0] = __builtin_amdgcn_mfma_f32_16x16x32_bf16(ah, bh0, acc[mf][0], 0,0,0);
        acc[mf][0] = __builtin_amdgcn_mfma_f32_16x16x32_bf16(ah, bl0, acc[mf][0], 0,0,0);
        acc[mf][0] = __builtin_amdgcn_mfma_f32_16x16x32_bf16(al, bh0, acc[mf][0], 0,0,0);
        acc[mf][1] = __builtin_amdgcn_mfma_f32_16x16x32_bf16(ah, bh1, acc[mf][1], 0,0,0);
        acc[mf][1] = __builtin_amdgcn_mfma_f32_16x16x32_bf16(ah, bl1, acc[mf][1], 0,0,0);
        acc[mf][1] = __builtin_amdgcn_mfma_f32_16x16x32_bf16(al, bh1, acc[mf][1], 0,0,0);
      }
    }
    if (st+1 < NT){
      int nxt = cur ^ 1;
      *(s8v*)&As[nxt][0][wsh0] = vh0;  *(s8v*)&As[nxt][0][wsh1] = vh1;
      *(s8v*)&As[nxt][1][wsh0] = vl0;  *(s8v*)&As[nxt][1][wsh1] = vl1;
    }
    __syncthreads();
  }

  int drow0 = (lane >> 4) * 4;
  #pragma unroll
  for (int nf=0; nf<2; nf++){
    int col = n0 + nf*16 + lrow;
    float scv = (EPI >= 1) ? sc[col] : 0.f;
    float shv = sh[col];
    #pragma unroll
    for (int mf=0; mf<4; mf++){
      #pragma unroll
      for (int r=0; r<4; r++){
        int row = m0 + mf*16 + drow0 + r;
        if (row >= mEnd) continue;
        float a = acc[mf][nf][r];
        if (EPI == 0){
          Cf[(size_t)row*N + col] = a + shv;
        } else if (EPI == 1){
          float v = fmaxf(a*scv + shv, 0.f);
          short hi = f2bf(v);
          Chi[(size_t)(row-cBase)*N + col] = hi;
          Clo[(size_t)(row-cBase)*N + col] = f2bf(v - bf2f(hi));
        } else {
          float v = fmaxf(a*scv + shv, 0.f) + residf[(size_t)row*N + col];
          Cf[(size_t)row*N + col] = v;
        }
      }
    }
  }
}

// ---------------- BN fold ----------------
__global__ void fold_kernel(
  const float* __restrict__ b1,  const float* __restrict__ g1,  const float* __restrict__ bb1,
  const float* __restrict__ m1,  const float* __restrict__ v1,
  const float* __restrict__ b2,  const float* __restrict__ g2,  const float* __restrict__ bb2,
  const float* __restrict__ m2,  const float* __restrict__ v2,
  const float* __restrict__ cb1, const float* __restrict__ cg1, const float* __restrict__ cbb1,
  const float* __restrict__ cm1, const float* __restrict__ cv1,
  const float* __restrict__ cb2, const float* __restrict__ cg2, const float* __restrict__ cbb2,
  const float* __restrict__ cm2, const float* __restrict__ cv2,
  float* __restrict__ sc1, float* __restrict__ sh1,
  float* __restrict__ sc2, float* __restrict__ sh2,
  float* __restrict__ csc1, float* __restrict__ csh1,
  float* __restrict__ csc2, float* __restrict__ csh2){
  int idx = blockIdx.x*256 + threadIdx.x;
  const int n1 = NLAY*512, n2 = NLAY*256;
  if (idx < n1){
    float s = g1[idx]*rsqrtf(v1[idx]+1e-5f);
    sc1[idx]=s; sh1[idx]=(b1[idx]-m1[idx])*s + bb1[idx];
  } else if (idx < n1+n2){
    int i = idx-n1;
    float s = g2[i]*rsqrtf(v2[i]+1e-5f);
    sc2[i]=s; sh2[i]=(b2[i]-m2[i])*s + bb2[i];
  } else if (idx < n1+n2+256){
    int i = idx-n1-n2;
    float s = cg1[i]*rsqrtf(cv1[i]+1e-5f);
    csc1[i]=s; csh1[i]=(cb1[i]-cm1[i])*s + cbb1[i];
  } else if (idx < n1+n2+256+128){
    int i = idx-n1-n2-256;
    float s = cg2[i]*rsqrtf(cv2[i]+1e-5f);
    csc2[i]=s; csh2[i]=(cb2[i]-cm2[i])*s + cbb2[i];
  }
}

// ---------------- LSTM pointwise ----------------
__global__ void lstm_kernel(const float* __restrict__ gates, float* __restrict__ cst,
                            float* __restrict__ qs){
  int idx = blockIdx.x*256 + threadIdx.x;
  int b = idx >> 8, j = idx & 255;
  const float* g = &gates[(size_t)b*1024];
  float ig = sigmoidf_(g[j]);
  float fg = sigmoidf_(g[j+256]);
  float gg = tanhf(g[j+512]);
  float og = sigmoidf_(g[j+768]);
  float c  = fg*cst[idx] + ig*gg;
  float hv = og*tanhf(c);
  cst[idx] = c;
  qs[(size_t)b*768 + j]       = hv;
  qs[(size_t)b*768 + 512 + j] = hv;
}

// ---------------- attention energy ----------------
__global__ void ener_kernel(const float* __restrict__ h, const float* __restrict__ qs,
                            const int* __restrict__ batch, float* __restrict__ ener){
  int node = (blockIdx.x*256 + threadIdx.x) >> 6;
  int lane = threadIdx.x & 63;
  if (node >= N_NODES) return;
  int b = batch[node];
  float4 hv = *(const float4*)&h[(size_t)node*HDIM + lane*4];
  float4 qv = *(const float4*)&qs[(size_t)b*768 + 512 + lane*4];
  float v = hv.x*qv.x + hv.y*qv.y + hv.z*qv.z + hv.w*qv.w;
  for (int off=32; off; off>>=1) v += __shfl_down(v, off);
  if (lane==0) ener[node] = v;
}

// ---------------- segment softmax + weighted sum r ----------------
__global__ void attn_r_kernel(const float* __restrict__ h, const float* __restrict__ ener,
                              const int* __restrict__ segs, float* __restrict__ qs){
  __shared__ float red[256];
  int g = blockIdx.x, t = threadIdx.x;
  int s = segs[g], e = segs[g+1];
  float m = -INFINITY;
  for (int i=s+t; i<e; i+=256) m = fmaxf(m, ener[i]);
  red[t]=m; __syncthreads();
  for (int o=128;o>0;o>>=1){ if (t<o) red[t]=fmaxf(red[t],red[t+o]); __syncthreads(); }
  m = red[0];
  float msel = (e > s) ? m : 0.0f;
  __syncthreads();
  float a = 0.f;
  for (int i=s+t; i<e; i+=256) a += expf(ener[i]-msel);
  red[t]=a; __syncthreads();
  for (int o=128;o>0;o>>=1){ if (t<o) red[t]+=red[t+o]; __syncthreads(); }
  float inv = 1.0f/(red[0] + 1e-16f);
  float racc = 0.f;
  for (int i=s;i<e;i++) racc += expf(ener[i]-msel) * h[(size_t)i*HDIM + t];
  qs[(size_t)g*768 + 256 + t] = racc*inv;
}

// ---------------- fused classifier ----------------
__global__ void classifier_kernel(const float* __restrict__ qs,
   const float* __restrict__ cW1, const float* __restrict__ csc1, const float* __restrict__ csh1,
   const float* __restrict__ cW2, const float* __restrict__ csc2, const float* __restrict__ csh2,
   const float* __restrict__ cW3, const float* __restrict__ cb3, float* __restrict__ out){
  __shared__ float sq[512];
  __shared__ float so1[256];
  __shared__ float so2[128];
  __shared__ float fr[256];
  int g = blockIdx.x, t = threadIdx.x;
  sq[t]     = qs[(size_t)g*768 + t];
  sq[t+256] = qs[(size_t)g*768 + 256 + t];
  __syncthreads();
  float acc = 0.f;
  for (int k=0;k<512;k++) acc += sq[k]*cW1[(size_t)k*256 + t];
  so1[t] = fmaxf(acc*csc1[t]+csh1[t], 0.f);
  __syncthreads();
  if (t < 128){
    float a2 = 0.f;
    for (int k=0;k<256;k++) a2 += so1[k]*cW2[(size_t)k*128 + t];
    so2[t] = fmaxf(a2*csc2[t]+csh2[t], 0.f);
  }
  __syncthreads();
  fr[t] = (t<128) ? so2[t]*cW3[t] : 0.f;
  __syncthreads();
  for (int o=128;o>0;o>>=1){ if (t<o) fr[t]+=fr[t+o]; __syncthreads(); }
  if (t==0) out[g] = fr[0] + cb3[0];
}

// ---------------- host ----------------
extern "C" void kernel_launch(void* const* d_in, const int* in_sizes, int n_in,
                              void* d_out, int out_size, void* d_ws, size_t ws_size,
                              hipStream_t stream){
  const float* x         = (const float*)d_in[0];
  const float* edge_attr = (const float*)d_in[1];
  const int*   edge_idx  = (const int*)  d_in[2];
  const int*   batch     = (const int*)  d_in[3];
  const float* atom_W    = (const float*)d_in[4];
  const float* atom_b    = (const float*)d_in[5];
  const float* bond_W    = (const float*)d_in[6];
  const float* bond_b    = (const float*)d_in[7];
  const float* eps       = (const float*)d_in[8];
  const float* W1        = (const float*)d_in[9];
  const float* b1        = (const float*)d_in[10];
  const float* bn1_g     = (const float*)d_in[11];
  const float* bn1_b     = (const float*)d_in[12];
  const float* bn1_m     = (const float*)d_in[13];
  const float* bn1_v     = (const float*)d_in[14];
  const float* W2        = (const float*)d_in[15];
  const float* b2        = (const float*)d_in[16];
  const float* bn_g      = (const float*)d_in[17];
  const float* bn_b      = (const float*)d_in[18];
  const float* bn_m      = (const float*)d_in[19];
  const float* bn_v      = (const float*)d_in[20];
  const float* lstm_Wih  = (const float*)d_in[21];
  const float* lstm_Whh  = (const float*)d_in[22];
  const float* lstm_bih  = (const float*)d_in[23];
  const float* lstm_bhh  = (const float*)d_in[24];
  const float* cW1       = (const float*)d_in[25];
  const float* cb1       = (const float*)d_in[26];
  const float* cbn1_g    = (const float*)d_in[27];
  const float* cbn1_b    = (const float*)d_in[28];
  const float* cbn1_m    = (const float*)d_in[29];
  const float* cbn1_v    = (const float*)d_in[30];
  const float* cW2       = (const float*)d_in[31];
  const float* cb2       = (const float*)d_in[32];
  const float* cbn2_g    = (const float*)d_in[33];
  const float* cbn2_b    = (const float*)d_in[34];
  const float* cbn2_m    = (const float*)d_in[35];
  const float* cbn2_v    = (const float*)d_in[36];
  const float* cW3       = (const float*)d_in[37];
  const float* cb3       = (const float*)d_in[38];

  const int* src = edge_idx;
  const int* dst = edge_idx + N_EDGES;

  char* ws = (char*)d_ws;
  size_t off = 0;
  auto alloc = [&](size_t bytes)->void*{
    void* p = ws + off; off += (bytes + 255) & ~(size_t)255; return p;
  };
  float* h       = (float*)alloc((size_t)N_NODES*HDIM*4);     // 102.4 MB fp32 master
  short* zh      = (short*)alloc((size_t)N_NODES*HDIM*2);     //  51.2 MB
  short* zl      = (short*)alloc((size_t)N_NODES*HDIM*2);     //  51.2 MB
  int*   row_ptr = (int*)  alloc((size_t)(N_NODES+1)*4);
  int*   cursor  = (int*)  alloc((size_t)N_NODES*4);
  int*   s_eid   = (int*)  alloc((size_t)N_EDGES*4);
  int*   segs    = (int*)  alloc((size_t)(NB+1)*4);
  short* W1ph    = (short*)alloc((size_t)NLAY*HDIM*2*HDIM*2);
  short* W1pl    = (short*)alloc((size_t)NLAY*HDIM*2*HDIM*2);
  short* W2ph    = (short*)alloc((size_t)NLAY*HDIM*2*HDIM*2);
  short* W2pl    = (short*)alloc((size_t)NLAY*HDIM*2*HDIM*2);
  float* sc1     = (float*)alloc(NLAY*512*4);
  float* sh1     = (float*)alloc(NLAY*512*4);
  float* sc2     = (float*)alloc(NLAY*256*4);
  float* sh2     = (float*)alloc(NLAY*256*4);
  float* csc1    = (float*)alloc(256*4);
  float* csh1    = (float*)alloc(256*4);
  float* csc2    = (float*)alloc(128*4);
  float* csh2    = (float*)alloc(128*4);

  if (off >= ws_size){
    sentinel_kernel<<<(out_size+255)/256, 256, 0, stream>>>((float*)d_out, out_size);
    return;
  }
  size_t remain = ws_size - off;

  // optional edge reorder buffers (19.2 MB) if space allows a decent chunk too
  const size_t RE_BYTES = (((size_t)N_EDGES*4 + 255)&~(size_t)255)
                        + (((size_t)N_EDGES*FBOND*4 + 255)&~(size_t)255);
  bool use_re = (remain >= RE_BYTES + (size_t)16384*2048 + 512);
  int*   s_src = nullptr;
  float* ea_r  = nullptr;
  if (use_re){
    s_src = (int*)  alloc((size_t)N_EDGES*4);
    ea_r  = (float*)alloc((size_t)N_EDGES*FBOND*4);
    remain = ws_size - off;
  }

  // adaptive c1 chunk (split pair) from remaining workspace
  size_t chMax = remain / (2*HDIM*2*2);   // 512 cols * 2 arrays * 2B per row
  int CH = (int)((chMax/64)*64);
  if (CH < 64){
    sentinel_kernel<<<(out_size+255)/256, 256, 0, stream>>>((float*)d_out, out_size);
    return;
  }
  if (CH > 100032) CH = 100032;
  short* c1h = (short*)alloc((size_t)CH*2*HDIM*2);
  short* c1l = (short*)alloc((size_t)CH*2*HDIM*2);

  // Set2Set scratch aliases zh (dead after last GEMM1); ener aliases zl.
  char*  zb      = (char*)(void*)zh;
  float* gates   = (float*)zb;                          // 16.78 MB
  float* qs      = (float*)(zb + 16777216);             // 12.58 MB
  float* cst     = (float*)(zb + 29360128);             //  4.19 MB
  short* qsh     = (short*)(zb + 33554432);             //  6.29 MB
  short* qsl     = (short*)(zb + 39845888);             //  6.29 MB
  short* Wch     = (short*)(zb + 46137344);             //  1.57 MB
  short* Wcl     = (short*)(zb + 47710208);             //  1.57 MB
  float* bias_c  = (float*)(zb + 49283072);             //  4 KB
  float* ener    = (float*)(void*)zl;

  // ---- prep: fold BN+bias, pack GNN weights (split hi/lo) ----
  fold_kernel<<<(NLAY*512+NLAY*256+256+128+255)/256, 256, 0, stream>>>(
      b1, bn1_g, bn1_b, bn1_m, bn1_v,
      b2, bn_g,  bn_b,  bn_m,  bn_v,
      cb1, cbn1_g, cbn1_b, cbn1_m, cbn1_v,
      cb2, cbn2_g, cbn2_b, cbn2_m, cbn2_v,
      sc1, sh1, sc2, sh2, csc1, csh1, csc2, csh2);
  for (int l=0; l<NLAY; l++){
    packB_kernel<<<(HDIM*2*HDIM)/256, 256, 0, stream>>>(
        W1 + (size_t)l*HDIM*2*HDIM, W1ph + (size_t)l*HDIM*2*HDIM, W1pl + (size_t)l*HDIM*2*HDIM, HDIM, 2*HDIM);
    packB_kernel<<<(HDIM*2*HDIM)/256, 256, 0, stream>>>(
        W2 + (size_t)l*HDIM*2*HDIM, W2ph + (size_t)l*HDIM*2*HDIM, W2pl + (size_t)l*HDIM*2*HDIM, 2*HDIM, HDIM);
  }

  // ---- embeddings ----
  atom_embed_kernel<<<N_NODES/8, 256, 0, stream>>>(x, atom_W, atom_b, h);

  // ---- CSR by dst + batch segment starts (+ optional edge reorder) ----
  hipMemsetAsync(cursor, 0, (size_t)N_NODES*4, stream);
  count_kernel<<<(N_EDGES+255)/256, 256, 0, stream>>>(dst, cursor, N_EDGES);
  scan_kernel<<<1, 1024, 0, stream>>>(cursor, row_ptr, N_NODES);
  hipMemcpyAsync(cursor, row_ptr, (size_t)N_NODES*4, hipMemcpyDeviceToDevice, stream);
  fill_kernel<<<(N_EDGES+255)/256, 256, 0, stream>>>(dst, cursor, s_eid, N_EDGES);
  segstart_kernel<<<(NB+256)/256, 256, 0, stream>>>(batch, segs, N_NODES, NB);
  if (use_re)
    reorder_kernel<<<(N_EDGES+255)/256, 256, 0, stream>>>(s_eid, src, edge_attr, s_src, ea_r, N_EDGES);

  // ---- GINE layers (c1 chunked through the adaptive buffer) ----
  for (int l=0; l<NLAY; l++){
    if (use_re)
      gine_msg_kernel<true><<<N_NODES/4, 256, 0, stream>>>(h, edge_attr, bond_W, bond_b,
          src, s_eid, s_src, ea_r, row_ptr, eps, l, zh, zl);
    else
      gine_msg_kernel<false><<<N_NODES/4, 256, 0, stream>>>(h, edge_attr, bond_W, bond_b,
          src, s_eid, s_src, ea_r, row_ptr, eps, l, zh, zl);
    for (int m0=0; m0<N_NODES; m0+=CH){
      int mEnd = min(N_NODES, m0+CH);
      int gyc  = (mEnd-m0+63)/64;
      gemm_mfma<1><<<dim3(4, gyc), 256, 0, stream>>>(
          zh, zl, W1ph + (size_t)l*HDIM*2*HDIM, W1pl + (size_t)l*HDIM*2*HDIM,
          m0, mEnd, 2*HDIM, HDIM, sc1 + l*512, sh1 + l*512,
          c1h, c1l, nullptr, nullptr, 0, m0);
      gemm_mfma<2><<<dim3(2, gyc), 256, 0, stream>>>(
          c1h, c1l, W2ph + (size_t)l*HDIM*2*HDIM, W2pl + (size_t)l*HDIM*2*HDIM,
          m0, mEnd, HDIM, 2*HDIM, sc2 + l*256, sh2 + l*256,
          nullptr, nullptr, h, h, m0, 0);
    }
  }

  // ---- Set2Set (scratch aliases zh/zl, now dead) ----
  packWcat_kernel<<<(768*1024+255)/256, 256, 0, stream>>>(lstm_Wih, lstm_Whh, lstm_bih, lstm_bhh,
                                                          Wch, Wcl, bias_c);
  hipMemsetAsync(qs,  0, (size_t)NB*768*4, stream);
  hipMemsetAsync(cst, 0, (size_t)NB*HDIM*4, stream);
  for (int sstep=0; sstep<3; sstep++){
    qs_pack_kernel<<<(NB*768)/256, 256, 0, stream>>>(qs, qsh, qsl);
    gemm_mfma<0><<<dim3(1024/128, NB/64), 256, 0, stream>>>(
        qsh, qsl, Wch, Wcl, 0, NB, 1024, 768, nullptr, bias_c,
        nullptr, nullptr, gates, nullptr, 0, 0);
    lstm_kernel<<<(NB*HDIM)/256, 256, 0, stream>>>(gates, cst, qs);
    ener_kernel<<<N_NODES/4, 256, 0, stream>>>(h, qs, batch, ener);
    attn_r_kernel<<<NB, 256, 0, stream>>>(h, ener, segs, qs);
  }

  // ---- classifier ----
  classifier_kernel<<<NB, 256, 0, stream>>>(qs, cW1, csc1, csh1, cW2, csc2, csh2,
                                            cW3, cb3, (float*)d_out);
}

// Round 7
// 3284.847 us; speedup vs baseline: 1.4623x; 1.0218x over previous
//
#include <hip/hip_runtime.h>
#include <hip/hip_bf16.h>

#define N_NODES 100000
#define N_EDGES 400000
#define NB      4096
#define FAT     30
#define FBOND   11
#define HDIM    256
#define NLAY    5
#define CK      128

typedef short s8v  __attribute__((ext_vector_type(8)));
typedef float f32x4 __attribute__((ext_vector_type(4)));

static __device__ __forceinline__ float sigmoidf_(float x){ return 1.0f/(1.0f+expf(-x)); }
static __device__ __forceinline__ float bf2f(short s){
  return __uint_as_float(((unsigned)(unsigned short)s) << 16);
}
static __device__ __forceinline__ short f2bf(float f){   // RNE
  unsigned u = __float_as_uint(f);
  u += 0x7fffu + ((u >> 16) & 1u);
  return (short)(u >> 16);
}

// ---------------- sentinel (ws too small diagnostic) ----------------
__global__ void sentinel_kernel(float* out, int n){
  int i = blockIdx.x*256 + threadIdx.x;
  if (i < n) out[i] = 12345.0f;
}

// ---------------- atom embedding: h = x @ atom_W + atom_b (fp32) ----------------
__global__ void atom_embed_kernel(const float* __restrict__ x, const float* __restrict__ W,
                                  const float* __restrict__ b, float* __restrict__ h){
  __shared__ float xs[8][FAT];
  int n0 = blockIdx.x * 8;
  int t = threadIdx.x;
  if (t < 8*FAT) xs[t/FAT][t%FAT] = x[(size_t)(n0 + t/FAT)*FAT + t%FAT];
  __syncthreads();
  int c = t;
  float acc[8];
  float bias = b[c];
  #pragma unroll
  for (int r=0;r<8;r++) acc[r]=bias;
  #pragma unroll
  for (int k=0;k<FAT;k++){
    float w = W[k*HDIM + c];
    #pragma unroll
    for (int r=0;r<8;r++) acc[r] += xs[r][k]*w;
  }
  #pragma unroll
  for (int r=0;r<8;r++) h[(size_t)(n0+r)*HDIM + c] = acc[r];
}

// ---------------- CSR build over dst ----------------
__global__ void count_kernel(const int* __restrict__ dst, int* __restrict__ counts, int E){
  int e = blockIdx.x*blockDim.x + threadIdx.x;
  if (e < E) atomicAdd(&counts[dst[e]], 1);
}

__global__ void scan_kernel(const int* __restrict__ counts, int* __restrict__ row_ptr, int n){
  __shared__ int part[1024];
  int t = threadIdx.x;
  int chunk = (n + 1023) >> 10;
  int s = t*chunk, e2 = min(s+chunk, n);
  int sum = 0;
  for (int i=s;i<e2;i++) sum += counts[i];
  part[t] = sum; __syncthreads();
  for (int off=1; off<1024; off<<=1){
    int v = (t>=off) ? part[t-off] : 0;
    __syncthreads();
    part[t] += v;
    __syncthreads();
  }
  int run = part[t]-sum;
  for (int i=s;i<e2;i++){ row_ptr[i]=run; run+=counts[i]; }
  if (e2==n && s<=n) row_ptr[n]=run;
}

__global__ void fill_kernel(const int* __restrict__ dst, int* __restrict__ cursor,
                            int* __restrict__ sorted_eid, int E){
  int e = blockIdx.x*blockDim.x + threadIdx.x;
  if (e < E){ int pos = atomicAdd(&cursor[dst[e]],1); sorted_eid[pos]=e; }
}

__global__ void segstart_kernel(const int* __restrict__ batch, int* __restrict__ segs, int n, int nb){
  int g = blockIdx.x*blockDim.x + threadIdx.x;
  if (g > nb) return;
  int lo=0, hi=n;
  while (lo<hi){ int mid=(lo+hi)>>1; if (batch[mid] < g) lo=mid+1; else hi=mid; }
  segs[g]=lo;
}

// ---------------- one-time edge reorder: linear src + edge_attr in CSR order -------
__global__ void reorder_kernel(const int* __restrict__ s_eid, const int* __restrict__ src,
                               const float* __restrict__ ea,
                               int* __restrict__ s_src, float* __restrict__ ea_r, int E){
  int i = blockIdx.x*256 + threadIdx.x;
  if (i >= E) return;
  int eid = s_eid[i];
  s_src[i] = src[eid];
  const float* a = ea + (size_t)eid*FBOND;
  float* o = ea_r + (size_t)i*FBOND;
  #pragma unroll
  for (int k=0;k<FBOND;k++) o[k] = a[k];
}

// ---------------- GINE message + aggregate (fp32 h -> split-bf16 z) ----------------
template<bool RE>
__global__ void gine_msg_kernel(const float* __restrict__ h, const float* __restrict__ ea,
                                const float* __restrict__ bW, const float* __restrict__ bb,
                                const int* __restrict__ src, const int* __restrict__ s_eid,
                                const int* __restrict__ s_src, const float* __restrict__ ea_r,
                                const int* __restrict__ row_ptr, const float* __restrict__ eps,
                                int layer, short* __restrict__ zh, short* __restrict__ zl){
  __shared__ float wB[FBOND][HDIM];
  __shared__ float bB[HDIM];
  int t = threadIdx.x;
  for (int i=t; i<FBOND*HDIM; i+=256) wB[i/HDIM][i%HDIM] = bW[i];
  if (t < HDIM) bB[t] = bb[t];
  __syncthreads();
  int node = (blockIdx.x*256 + t) >> 6;
  int lane = t & 63;
  if (node >= N_NODES) return;
  int c0 = lane*4;
  float4 hv = *(const float4*)&h[(size_t)node*HDIM + c0];
  float epsf = 1.0f + eps[layer];
  float ax = hv.x*epsf, ay = hv.y*epsf, az = hv.z*epsf, aw = hv.w*epsf;
  int s = row_ptr[node], e = row_ptr[node+1];
  for (int idx=s; idx<e; idx++){
    int sn; const float* earow;
    if (RE){ sn = s_src[idx];                 earow = ea_r + (size_t)idx*FBOND; }
    else   { int eid = s_eid[idx]; sn = src[eid]; earow = ea + (size_t)eid*FBOND; }
    float4 hs = *(const float4*)&h[(size_t)sn*HDIM + c0];
    float ex = bB[c0], ey = bB[c0+1], ez = bB[c0+2], ew = bB[c0+3];
    #pragma unroll
    for (int k=0;k<FBOND;k++){
      float a = earow[k];
      float4 w = *(const float4*)&wB[k][c0];
      ex += a*w.x; ey += a*w.y; ez += a*w.z; ew += a*w.w;
    }
    ax += fmaxf(hs.x+ex, 0.f);
    ay += fmaxf(hs.y+ey, 0.f);
    az += fmaxf(hs.z+ez, 0.f);
    aw += fmaxf(hs.w+ew, 0.f);
  }
  short4 oh, ol;
  oh.x=f2bf(ax); ol.x=f2bf(ax-bf2f(oh.x));
  oh.y=f2bf(ay); ol.y=f2bf(ay-bf2f(oh.y));
  oh.z=f2bf(az); ol.z=f2bf(az-bf2f(oh.z));
  oh.w=f2bf(aw); ol.w=f2bf(aw-bf2f(oh.w));
  *(short4*)&zh[(size_t)node*HDIM + c0] = oh;
  *(short4*)&zl[(size_t)node*HDIM + c0] = ol;
}

// ---------------- pack weights into MFMA B-fragment layout, split hi/lo -------------
__global__ void packB_kernel(const float* __restrict__ B, short* __restrict__ Bph,
                             short* __restrict__ Bpl, int K, int N){
  int idx = blockIdx.x*256 + threadIdx.x;
  if (idx >= K*N) return;
  int b    = idx & 7;
  int lane = (idx >> 3) & 63;
  int t2   = idx >> 9;
  int KT   = K >> 5;
  int kt   = t2 % KT, nt = t2 / KT;
  int k = kt*32 + ((lane>>4)<<3) + b;
  int n = nt*16 + (lane&15);
  float w = B[(size_t)k*N + n];
  short hi = f2bf(w);
  Bph[idx] = hi;
  Bpl[idx] = f2bf(w - bf2f(hi));
}

// ---------------- pack LSTM [Wih|Whh]^T (K=768, N=1024) + bias, split hi/lo --------
__global__ void packWcat_kernel(const float* __restrict__ Wih, const float* __restrict__ Whh,
                                const float* __restrict__ bih, const float* __restrict__ bhh,
                                short* __restrict__ Wch, short* __restrict__ Wcl,
                                float* __restrict__ bias_c){
  int idx = blockIdx.x*256 + threadIdx.x;
  if (idx < 1024) bias_c[idx] = bih[idx] + bhh[idx];
  if (idx >= 768*1024) return;
  int b    = idx & 7;
  int lane = (idx >> 3) & 63;
  int t2   = idx >> 9;
  const int KT = 24;
  int kt   = t2 % KT, nt = t2 / KT;
  int k = kt*32 + ((lane>>4)<<3) + b;
  int n = nt*16 + (lane&15);
  float w = (k < 512) ? Wih[(size_t)n*512 + k] : Whh[(size_t)n*256 + (k-512)];
  short hi = f2bf(w);
  Wch[idx] = hi;
  Wcl[idx] = f2bf(w - bf2f(hi));
}

// ---------------- split-bf16 MFMA GEMM, LDS-staged A, double-buffered --------------
// acc += ah*bh + ah*bl + al*bh  (fp32-grade). K multiple of 64.
// block: 4 waves, tile 64(M) x 128(N); wave tile 64x32.
// EPI 0: Cf = acc + sh[col]                     (bias only, fp32 out)
// EPI 1: v = relu(acc*sc+sh) -> split (Chi,Clo) at row-cBase
// EPI 2: v = relu(acc*sc+sh) + residf -> fp32 Cf at absolute row
template<int EPI>
__launch_bounds__(256)
__global__ void gemm_mfma(const short* __restrict__ Ah, const short* __restrict__ Al,
                          const short* __restrict__ Bh, const short* __restrict__ Bl,
                          int mBase, int mEnd, int N, int K,
                          const float* __restrict__ sc, const float* __restrict__ sh,
                          short* __restrict__ Chi, short* __restrict__ Clo,
                          float* __restrict__ Cf, const float* __restrict__ residf,
                          int aBase, int cBase){
  __shared__ short As[2][2][64*72];   // [dbuf][hi/lo][row*72 + k], row stride 144B
  int t    = threadIdx.x;
  int lane = t & 63;
  int wid  = t >> 6;
  int m0 = mBase + blockIdx.y * 64;
  int n0 = blockIdx.x * 128 + wid * 32;
  int lrow = lane & 15;
  int lk8  = (lane >> 4) << 3;
  int KT = K >> 5;
  int NT = K >> 6;

  f32x4 acc[4][2];
  #pragma unroll
  for (int i=0;i<4;i++)
    #pragma unroll
    for (int j=0;j<2;j++) acc[i][j] = (f32x4){0.f,0.f,0.f,0.f};

  // staging: 2 chunks/thread, rows r0=t>>3 (0..31) and r0+32, 16B chunk c8=t&7
  int r0 = t >> 3, c8 = t & 7;
  int gr0 = min(m0 + r0,      mEnd-1) - aBase;
  int gr1 = min(m0 + r0 + 32, mEnd-1) - aBase;
  const short* pa0h = Ah + (size_t)gr0*K + c8*8;
  const short* pa0l = Al + (size_t)gr0*K + c8*8;
  const short* pa1h = Ah + (size_t)gr1*K + c8*8;
  const short* pa1l = Al + (size_t)gr1*K + c8*8;
  int wsh0 = r0*72 + c8*8;
  int wsh1 = (r0+32)*72 + c8*8;

  size_t boff = ((size_t)(n0 >> 4) * KT) * 512 + lane*8;

  // prologue: stage 0
  s8v vh0 = *(const s8v*)(pa0h);
  s8v vh1 = *(const s8v*)(pa1h);
  s8v vl0 = *(const s8v*)(pa0l);
  s8v vl1 = *(const s8v*)(pa1l);
  *(s8v*)&As[0][0][wsh0] = vh0;  *(s8v*)&As[0][0][wsh1] = vh1;
  *(s8v*)&As[0][1][wsh0] = vl0;  *(s8v*)&As[0][1][wsh1] = vl1;
  __syncthreads();

  for (int st=0; st<NT; ++st){
    int cur = st & 1;
    if (st+1 < NT){                       // issue next-stage loads early (hide under MFMA)
      int ko = (st+1)*64;
      vh0 = *(const s8v*)(pa0h + ko);
      vh1 = *(const s8v*)(pa1h + ko);
      vl0 = *(const s8v*)(pa0l + ko);
      vl1 = *(const s8v*)(pa1l + ko);
    }
    #pragma unroll
    for (int ktl=0; ktl<2; ++ktl){
      int kt = st*2 + ktl;
      s8v bh0 = *(const s8v*)(Bh + boff + (size_t)kt*512);
      s8v bl0 = *(const s8v*)(Bl + boff + (size_t)kt*512);
      s8v bh1 = *(const s8v*)(Bh + boff + (size_t)(KT + kt)*512);
      s8v bl1 = *(const s8v*)(Bl + boff + (size_t)(KT + kt)*512);
      int ksh = ktl*32 + lk8;
      #pragma unroll
      for (int mf=0; mf<4; ++mf){
        int rsh = (mf*16 + lrow)*72 + ksh;
        s8v ah = *(const s8v*)&As[cur][0][rsh];
        s8v al = *(const s8v*)&As[cur][1][rsh];
        acc[mf][0] = __builtin_amdgcn_mfma_f32_16x16x32_bf16(ah, bh0, acc[mf][0], 0,0,0);
        acc[mf][0] = __builtin_amdgcn_mfma_f32_16x16x32_bf16(ah, bl0, acc[mf][0], 0,0,0);
        acc[mf][0] = __builtin_amdgcn_mfma_f32_16x16x32_bf16(al, bh0, acc[mf][0], 0,0,0);
        acc[mf][1] = __builtin_amdgcn_mfma_f32_16x16x32_bf16(ah, bh1, acc[mf][1], 0,0,0);
        acc[mf][1] = __builtin_amdgcn_mfma_f32_16x16x32_bf16(ah, bl1, acc[mf][1], 0,0,0);
        acc[mf][1] = __builtin_amdgcn_mfma_f32_16x16x32_bf16(al, bh1, acc[mf][1], 0,0,0);
      }
    }
    if (st+1 < NT){
      int nxt = cur ^ 1;
      *(s8v*)&As[nxt][0][wsh0] = vh0;  *(s8v*)&As[nxt][0][wsh1] = vh1;
      *(s8v*)&As[nxt][1][wsh0] = vl0;  *(s8v*)&As[nxt][1][wsh1] = vl1;
    }
    __syncthreads();
  }

  int drow0 = (lane >> 4) * 4;
  #pragma unroll
  for (int nf=0; nf<2; nf++){
    int col = n0 + nf*16 + lrow;
    float scv = (EPI >= 1) ? sc[col] : 0.f;
    float shv = sh[col];
    #pragma unroll
    for (int mf=0; mf<4; mf++){
      #pragma unroll
      for (int r=0; r<4; r++){
        int row = m0 + mf*16 + drow0 + r;
        if (row >= mEnd) continue;
        float a = acc[mf][nf][r];
        if (EPI == 0){
          Cf[(size_t)row*N + col] = a + shv;
        } else if (EPI == 1){
          float v = fmaxf(a*scv + shv, 0.f);
          short hi = f2bf(v);
          Chi[(size_t)(row-cBase)*N + col] = hi;
          Clo[(size_t)(row-cBase)*N + col] = f2bf(v - bf2f(hi));
        } else {
          float v = fmaxf(a*scv + shv, 0.f) + residf[(size_t)row*N + col];
          Cf[(size_t)row*N + col] = v;
        }
      }
    }
  }
}

// ---------------- BN fold ----------------
__global__ void fold_kernel(
  const float* __restrict__ b1,  const float* __restrict__ g1,  const float* __restrict__ bb1,
  const float* __restrict__ m1,  const float* __restrict__ v1,
  const float* __restrict__ b2,  const float* __restrict__ g2,  const float* __restrict__ bb2,
  const float* __restrict__ m2,  const float* __restrict__ v2,
  const float* __restrict__ cb1, const float* __restrict__ cg1, const float* __restrict__ cbb1,
  const float* __restrict__ cm1, const float* __restrict__ cv1,
  const float* __restrict__ cb2, const float* __restrict__ cg2, const float* __restrict__ cbb2,
  const float* __restrict__ cm2, const float* __restrict__ cv2,
  float* __restrict__ sc1, float* __restrict__ sh1,
  float* __restrict__ sc2, float* __restrict__ sh2,
  float* __restrict__ csc1, float* __restrict__ csh1,
  float* __restrict__ csc2, float* __restrict__ csh2){
  int idx = blockIdx.x*256 + threadIdx.x;
  const int n1 = NLAY*512, n2 = NLAY*256;
  if (idx < n1){
    float s = g1[idx]*rsqrtf(v1[idx]+1e-5f);
    sc1[idx]=s; sh1[idx]=(b1[idx]-m1[idx])*s + bb1[idx];
  } else if (idx < n1+n2){
    int i = idx-n1;
    float s = g2[i]*rsqrtf(v2[i]+1e-5f);
    sc2[i]=s; sh2[i]=(b2[i]-m2[i])*s + bb2[i];
  } else if (idx < n1+n2+256){
    int i = idx-n1-n2;
    float s = cg1[i]*rsqrtf(cv1[i]+1e-5f);
    csc1[i]=s; csh1[i]=(cb1[i]-cm1[i])*s + cbb1[i];
  } else if (idx < n1+n2+256+128){
    int i = idx-n1-n2-256;
    float s = cg2[i]*rsqrtf(cv2[i]+1e-5f);
    csc2[i]=s; csh2[i]=(cb2[i]-cm2[i])*s + cbb2[i];
  }
}

// ---------------- LSTM pointwise (writes q/hst fp32 + split) ----------------
__global__ void lstm_kernel(const float* __restrict__ gates, float* __restrict__ cst,
                            float* __restrict__ qs, short* __restrict__ qsh,
                            short* __restrict__ qsl){
  int idx = blockIdx.x*256 + threadIdx.x;
  int b = idx >> 8, j = idx & 255;
  const float* g = &gates[(size_t)b*1024];
  float ig = sigmoidf_(g[j]);
  float fg = sigmoidf_(g[j+256]);
  float gg = tanhf(g[j+512]);
  float og = sigmoidf_(g[j+768]);
  float c  = fg*cst[idx] + ig*gg;
  float hv = og*tanhf(c);
  cst[idx] = c;
  size_t base = (size_t)b*768;
  qs[base + j]       = hv;
  qs[base + 512 + j] = hv;
  short hi = f2bf(hv);
  short lo = f2bf(hv - bf2f(hi));
  qsh[base + j] = hi;        qsl[base + j] = lo;
  qsh[base + 512 + j] = hi;  qsl[base + 512 + j] = lo;
}

// ---------------- fused attention: ener + segment softmax + weighted r ----------------
// one block per graph; online softmax over CK-node chunks; writes r fp32 + split.
__global__ void attn_fused_kernel(const float* __restrict__ h, float* __restrict__ qs,
                                  short* __restrict__ qsh, short* __restrict__ qsl,
                                  const int* __restrict__ segs){
  __shared__ float en[CK];
  __shared__ float red[256];
  __shared__ float hstS[HDIM];
  int g = blockIdx.x, t = threadIdx.x;
  int s = segs[g], e = segs[g+1];
  int lane = t & 63, w = t >> 6;
  if (t < HDIM) hstS[t] = qs[(size_t)g*768 + 512 + t];
  __syncthreads();
  float4 hq = *(const float4*)&hstS[lane*4];
  float m_run = -INFINITY, s_run = 0.f, racc = 0.f;
  for (int base = s; base < e; base += CK){
    int cnt = min(e - base, CK);
    // dots: wave w handles local nodes w, w+4, ...
    for (int li = w; li < cnt; li += 4){
      float4 hv = *(const float4*)&h[(size_t)(base+li)*HDIM + lane*4];
      float v = hv.x*hq.x + hv.y*hq.y + hv.z*hq.z + hv.w*hq.w;
      for (int o=32; o; o>>=1) v += __shfl_down(v, o);
      if (lane==0) en[li] = v;
    }
    __syncthreads();
    // chunk max
    red[t] = (t < cnt) ? en[t] : -INFINITY;
    __syncthreads();
    for (int o=128;o>0;o>>=1){ if (t<o) red[t]=fmaxf(red[t],red[t+o]); __syncthreads(); }
    float nm = fmaxf(m_run, red[0]);
    __syncthreads();
    // chunk exp-sum
    float ce = (t < cnt) ? expf(en[t]-nm) : 0.f;
    red[t] = ce; __syncthreads();
    for (int o=128;o>0;o>>=1){ if (t<o) red[t]+=red[t+o]; __syncthreads(); }
    float csum = red[0];
    __syncthreads();
    if (t < cnt) en[t] = ce;   // stash exp weights
    __syncthreads();
    float scale = (m_run == -INFINITY) ? 0.f : expf(m_run - nm);
    s_run = s_run*scale + csum;
    racc  = racc*scale;
    for (int j=0;j<cnt;j++)
      racc += en[j] * h[(size_t)(base+j)*HDIM + t];
    m_run = nm;
    __syncthreads();
  }
  float r = racc / (s_run + 1e-16f);
  size_t o = (size_t)g*768 + 256 + t;
  qs[o] = r;
  short hi = f2bf(r);
  qsh[o] = hi;
  qsl[o] = f2bf(r - bf2f(hi));
}

// ---------------- fused classifier ----------------
__global__ void classifier_kernel(const float* __restrict__ qs,
   const float* __restrict__ cW1, const float* __restrict__ csc1, const float* __restrict__ csh1,
   const float* __restrict__ cW2, const float* __restrict__ csc2, const float* __restrict__ csh2,
   const float* __restrict__ cW3, const float* __restrict__ cb3, float* __restrict__ out){
  __shared__ float sq[512];
  __shared__ float so1[256];
  __shared__ float so2[128];
  __shared__ float fr[256];
  int g = blockIdx.x, t = threadIdx.x;
  sq[t]     = qs[(size_t)g*768 + t];
  sq[t+256] = qs[(size_t)g*768 + 256 + t];
  __syncthreads();
  float acc = 0.f;
  for (int k=0;k<512;k++) acc += sq[k]*cW1[(size_t)k*256 + t];
  so1[t] = fmaxf(acc*csc1[t]+csh1[t], 0.f);
  __syncthreads();
  if (t < 128){
    float a2 = 0.f;
    for (int k=0;k<256;k++) a2 += so1[k]*cW2[(size_t)k*128 + t];
    so2[t] = fmaxf(a2*csc2[t]+csh2[t], 0.f);
  }
  __syncthreads();
  fr[t] = (t<128) ? so2[t]*cW3[t] : 0.f;
  __syncthreads();
  for (int o=128;o>0;o>>=1){ if (t<o) fr[t]+=fr[t+o]; __syncthreads(); }
  if (t==0) out[g] = fr[0] + cb3[0];
}

// ---------------- host ----------------
extern "C" void kernel_launch(void* const* d_in, const int* in_sizes, int n_in,
                              void* d_out, int out_size, void* d_ws, size_t ws_size,
                              hipStream_t stream){
  const float* x         = (const float*)d_in[0];
  const float* edge_attr = (const float*)d_in[1];
  const int*   edge_idx  = (const int*)  d_in[2];
  const int*   batch     = (const int*)  d_in[3];
  const float* atom_W    = (const float*)d_in[4];
  const float* atom_b    = (const float*)d_in[5];
  const float* bond_W    = (const float*)d_in[6];
  const float* bond_b    = (const float*)d_in[7];
  const float* eps       = (const float*)d_in[8];
  const float* W1        = (const float*)d_in[9];
  const float* b1        = (const float*)d_in[10];
  const float* bn1_g     = (const float*)d_in[11];
  const float* bn1_b     = (const float*)d_in[12];
  const float* bn1_m     = (const float*)d_in[13];
  const float* bn1_v     = (const float*)d_in[14];
  const float* W2        = (const float*)d_in[15];
  const float* b2        = (const float*)d_in[16];
  const float* bn_g      = (const float*)d_in[17];
  const float* bn_b      = (const float*)d_in[18];
  const float* bn_m      = (const float*)d_in[19];
  const float* bn_v      = (const float*)d_in[20];
  const float* lstm_Wih  = (const float*)d_in[21];
  const float* lstm_Whh  = (const float*)d_in[22];
  const float* lstm_bih  = (const float*)d_in[23];
  const float* lstm_bhh  = (const float*)d_in[24];
  const float* cW1       = (const float*)d_in[25];
  const float* cb1       = (const float*)d_in[26];
  const float* cbn1_g    = (const float*)d_in[27];
  const float* cbn1_b    = (const float*)d_in[28];
  const float* cbn1_m    = (const float*)d_in[29];
  const float* cbn1_v    = (const float*)d_in[30];
  const float* cW2       = (const float*)d_in[31];
  const float* cb2       = (const float*)d_in[32];
  const float* cbn2_g    = (const float*)d_in[33];
  const float* cbn2_b    = (const float*)d_in[34];
  const float* cbn2_m    = (const float*)d_in[35];
  const float* cbn2_v    = (const float*)d_in[36];
  const float* cW3       = (const float*)d_in[37];
  const float* cb3       = (const float*)d_in[38];

  const int* src = edge_idx;
  const int* dst = edge_idx + N_EDGES;

  char* ws = (char*)d_ws;
  size_t off = 0;
  auto alloc = [&](size_t bytes)->void*{
    void* p = ws + off; off += (bytes + 255) & ~(size_t)255; return p;
  };
  float* h       = (float*)alloc((size_t)N_NODES*HDIM*4);     // 102.4 MB fp32 master
  short* zh      = (short*)alloc((size_t)N_NODES*HDIM*2);     //  51.2 MB
  short* zl      = (short*)alloc((size_t)N_NODES*HDIM*2);     //  51.2 MB
  int*   row_ptr = (int*)  alloc((size_t)(N_NODES+1)*4);
  int*   cursor  = (int*)  alloc((size_t)N_NODES*4);
  int*   s_eid   = (int*)  alloc((size_t)N_EDGES*4);
  int*   segs    = (int*)  alloc((size_t)(NB+1)*4);
  short* W1ph    = (short*)alloc((size_t)NLAY*HDIM*2*HDIM*2);
  short* W1pl    = (short*)alloc((size_t)NLAY*HDIM*2*HDIM*2);
  short* W2ph    = (short*)alloc((size_t)NLAY*HDIM*2*HDIM*2);
  short* W2pl    = (short*)alloc((size_t)NLAY*HDIM*2*HDIM*2);
  float* sc1     = (float*)alloc(NLAY*512*4);
  float* sh1     = (float*)alloc(NLAY*512*4);
  float* sc2     = (float*)alloc(NLAY*256*4);
  float* sh2     = (float*)alloc(NLAY*256*4);
  float* csc1    = (float*)alloc(256*4);
  float* csh1    = (float*)alloc(256*4);
  float* csc2    = (float*)alloc(128*4);
  float* csh2    = (float*)alloc(128*4);

  if (off >= ws_size){
    sentinel_kernel<<<(out_size+255)/256, 256, 0, stream>>>((float*)d_out, out_size);
    return;
  }
  size_t remain = ws_size - off;

  // optional edge reorder buffers (19.2 MB) if space allows a decent chunk too
  const size_t RE_BYTES = (((size_t)N_EDGES*4 + 255)&~(size_t)255)
                        + (((size_t)N_EDGES*FBOND*4 + 255)&~(size_t)255);
  bool use_re = (remain >= RE_BYTES + (size_t)16384*2048 + 512);
  int*   s_src = nullptr;
  float* ea_r  = nullptr;
  if (use_re){
    s_src = (int*)  alloc((size_t)N_EDGES*4);
    ea_r  = (float*)alloc((size_t)N_EDGES*FBOND*4);
    remain = ws_size - off;
  }

  // adaptive c1 chunk (split pair); clamp so the c1 chunk stays L3-resident
  size_t chMax = remain / (2*HDIM*2*2);   // 512 cols * 2 arrays * 2B per row
  int CH = (int)((chMax/64)*64);
  if (CH < 64){
    sentinel_kernel<<<(out_size+255)/256, 256, 0, stream>>>((float*)d_out, out_size);
    return;
  }
  if (CH > 24576) CH = 24576;             // c1 chunk = 50.3 MB << 256 MB L3
  short* c1h = (short*)alloc((size_t)CH*2*HDIM*2);
  short* c1l = (short*)alloc((size_t)CH*2*HDIM*2);

  // Set2Set scratch aliases zh (dead after last GEMM1).
  char*  zb      = (char*)(void*)zh;
  float* gates   = (float*)zb;                          // 16.78 MB
  float* qs      = (float*)(zb + 16777216);             // 12.58 MB
  float* cst     = (float*)(zb + 29360128);             //  4.19 MB
  short* qsh     = (short*)(zb + 33554432);             //  6.29 MB
  short* qsl     = (short*)(zb + 39845888);             //  6.29 MB
  short* Wch     = (short*)(zb + 46137344);             //  1.57 MB
  short* Wcl     = (short*)(zb + 47710208);             //  1.57 MB
  float* bias_c  = (float*)(zb + 49283072);             //  4 KB

  // ---- prep: fold BN+bias, pack GNN weights (split hi/lo) ----
  fold_kernel<<<(NLAY*512+NLAY*256+256+128+255)/256, 256, 0, stream>>>(
      b1, bn1_g, bn1_b, bn1_m, bn1_v,
      b2, bn_g,  bn_b,  bn_m,  bn_v,
      cb1, cbn1_g, cbn1_b, cbn1_m, cbn1_v,
      cb2, cbn2_g, cbn2_b, cbn2_m, cbn2_v,
      sc1, sh1, sc2, sh2, csc1, csh1, csc2, csh2);
  for (int l=0; l<NLAY; l++){
    packB_kernel<<<(HDIM*2*HDIM)/256, 256, 0, stream>>>(
        W1 + (size_t)l*HDIM*2*HDIM, W1ph + (size_t)l*HDIM*2*HDIM, W1pl + (size_t)l*HDIM*2*HDIM, HDIM, 2*HDIM);
    packB_kernel<<<(HDIM*2*HDIM)/256, 256, 0, stream>>>(
        W2 + (size_t)l*HDIM*2*HDIM, W2ph + (size_t)l*HDIM*2*HDIM, W2pl + (size_t)l*HDIM*2*HDIM, 2*HDIM, HDIM);
  }

  // ---- embeddings ----
  atom_embed_kernel<<<N_NODES/8, 256, 0, stream>>>(x, atom_W, atom_b, h);

  // ---- CSR by dst + batch segment starts (+ optional edge reorder) ----
  hipMemsetAsync(cursor, 0, (size_t)N_NODES*4, stream);
  count_kernel<<<(N_EDGES+255)/256, 256, 0, stream>>>(dst, cursor, N_EDGES);
  scan_kernel<<<1, 1024, 0, stream>>>(cursor, row_ptr, N_NODES);
  hipMemcpyAsync(cursor, row_ptr, (size_t)N_NODES*4, hipMemcpyDeviceToDevice, stream);
  fill_kernel<<<(N_EDGES+255)/256, 256, 0, stream>>>(dst, cursor, s_eid, N_EDGES);
  segstart_kernel<<<(NB+256)/256, 256, 0, stream>>>(batch, segs, N_NODES, NB);
  if (use_re)
    reorder_kernel<<<(N_EDGES+255)/256, 256, 0, stream>>>(s_eid, src, edge_attr, s_src, ea_r, N_EDGES);

  // ---- GINE layers (c1 chunked; chunk sized for L3 residency) ----
  for (int l=0; l<NLAY; l++){
    if (use_re)
      gine_msg_kernel<true><<<N_NODES/4, 256, 0, stream>>>(h, edge_attr, bond_W, bond_b,
          src, s_eid, s_src, ea_r, row_ptr, eps, l, zh, zl);
    else
      gine_msg_kernel<false><<<N_NODES/4, 256, 0, stream>>>(h, edge_attr, bond_W, bond_b,
          src, s_eid, s_src, ea_r, row_ptr, eps, l, zh, zl);
    for (int m0=0; m0<N_NODES; m0+=CH){
      int mEnd = min(N_NODES, m0+CH);
      int gyc  = (mEnd-m0+63)/64;
      gemm_mfma<1><<<dim3(4, gyc), 256, 0, stream>>>(
          zh, zl, W1ph + (size_t)l*HDIM*2*HDIM, W1pl + (size_t)l*HDIM*2*HDIM,
          m0, mEnd, 2*HDIM, HDIM, sc1 + l*512, sh1 + l*512,
          c1h, c1l, nullptr, nullptr, 0, m0);
      gemm_mfma<2><<<dim3(2, gyc), 256, 0, stream>>>(
          c1h, c1l, W2ph + (size_t)l*HDIM*2*HDIM, W2pl + (size_t)l*HDIM*2*HDIM,
          m0, mEnd, HDIM, 2*HDIM, sc2 + l*256, sh2 + l*256,
          nullptr, nullptr, h, h, m0, 0);
    }
  }

  // ---- Set2Set (scratch aliases zh, now dead) ----
  packWcat_kernel<<<(768*1024+255)/256, 256, 0, stream>>>(lstm_Wih, lstm_Whh, lstm_bih, lstm_bhh,
                                                          Wch, Wcl, bias_c);
  hipMemsetAsync(qsh, 0, (size_t)NB*768*2, stream);
  hipMemsetAsync(qsl, 0, (size_t)NB*768*2, stream);
  hipMemsetAsync(cst, 0, (size_t)NB*HDIM*4, stream);
  for (int sstep=0; sstep<3; sstep++){
    gemm_mfma<0><<<dim3(1024/128, NB/64), 256, 0, stream>>>(
        qsh, qsl, Wch, Wcl, 0, NB, 1024, 768, nullptr, bias_c,
        nullptr, nullptr, gates, nullptr, 0, 0);
    lstm_kernel<<<(NB*HDIM)/256, 256, 0, stream>>>(gates, cst, qs, qsh, qsl);
    attn_fused_kernel<<<NB, 256, 0, stream>>>(h, qs, qsh, qsl, segs);
  }

  // ---- classifier ----
  classifier_kernel<<<NB, 256, 0, stream>>>(qs, cW1, csc1, csh1, cW2, csc2, csh2,
                                            cW3, cb3, (float*)d_out);
}

// Round 9
// 2390.182 us; speedup vs baseline: 2.0096x; 1.3743x over previous
//
#include <hip/hip_runtime.h>
#include <hip/hip_bf16.h>

#define N_NODES 100000
#define N_EDGES 400000
#define NB      4096
#define FAT     30
#define FBOND   11
#define HDIM    256
#define NLAY    5
#define CK      128

typedef short s8v  __attribute__((ext_vector_type(8)));
typedef float f32x4 __attribute__((ext_vector_type(4)));

static __device__ __forceinline__ float sigmoidf_(float x){ return 1.0f/(1.0f+expf(-x)); }
static __device__ __forceinline__ float bf2f(short s){
  return __uint_as_float(((unsigned)(unsigned short)s) << 16);
}
static __device__ __forceinline__ short f2bf(float f){   // RNE
  unsigned u = __float_as_uint(f);
  u += 0x7fffu + ((u >> 16) & 1u);
  return (short)(u >> 16);
}

// ---------------- sentinel (ws too small diagnostic) ----------------
__global__ void sentinel_kernel(float* out, int n){
  int i = blockIdx.x*256 + threadIdx.x;
  if (i < n) out[i] = 12345.0f;
}

// ---------------- atom embedding: h = x @ atom_W + atom_b (fp32) ----------------
__global__ void atom_embed_kernel(const float* __restrict__ x, const float* __restrict__ W,
                                  const float* __restrict__ b, float* __restrict__ h){
  __shared__ float xs[8][FAT];
  int n0 = blockIdx.x * 8;
  int t = threadIdx.x;
  if (t < 8*FAT) xs[t/FAT][t%FAT] = x[(size_t)(n0 + t/FAT)*FAT + t%FAT];
  __syncthreads();
  int c = t;
  float acc[8];
  float bias = b[c];
  #pragma unroll
  for (int r=0;r<8;r++) acc[r]=bias;
  #pragma unroll
  for (int k=0;k<FAT;k++){
    float w = W[k*HDIM + c];
    #pragma unroll
    for (int r=0;r<8;r++) acc[r] += xs[r][k]*w;
  }
  #pragma unroll
  for (int r=0;r<8;r++) h[(size_t)(n0+r)*HDIM + c] = acc[r];
}

// ---------------- CSR build over dst ----------------
__global__ void count_kernel(const int* __restrict__ dst, int* __restrict__ counts, int E){
  int e = blockIdx.x*blockDim.x + threadIdx.x;
  if (e < E) atomicAdd(&counts[dst[e]], 1);
}

__global__ void scan_kernel(const int* __restrict__ counts, int* __restrict__ row_ptr, int n){
  __shared__ int part[1024];
  int t = threadIdx.x;
  int chunk = (n + 1023) >> 10;
  int s = t*chunk, e2 = min(s+chunk, n);
  int sum = 0;
  for (int i=s;i<e2;i++) sum += counts[i];
  part[t] = sum; __syncthreads();
  for (int off=1; off<1024; off<<=1){
    int v = (t>=off) ? part[t-off] : 0;
    __syncthreads();
    part[t] += v;
    __syncthreads();
  }
  int run = part[t]-sum;
  for (int i=s;i<e2;i++){ row_ptr[i]=run; run+=counts[i]; }
  if (e2==n && s<=n) row_ptr[n]=run;
}

__global__ void fill_kernel(const int* __restrict__ dst, int* __restrict__ cursor,
                            int* __restrict__ sorted_eid, int E){
  int e = blockIdx.x*blockDim.x + threadIdx.x;
  if (e < E){ int pos = atomicAdd(&cursor[dst[e]],1); sorted_eid[pos]=e; }
}

__global__ void segstart_kernel(const int* __restrict__ batch, int* __restrict__ segs, int n, int nb){
  int g = blockIdx.x*blockDim.x + threadIdx.x;
  if (g > nb) return;
  int lo=0, hi=n;
  while (lo<hi){ int mid=(lo+hi)>>1; if (batch[mid] < g) lo=mid+1; else hi=mid; }
  segs[g]=lo;
}

// ---------------- one-time edge reorder: linear src + edge_attr (stride 12) -------
__global__ void reorder_kernel(const int* __restrict__ s_eid, const int* __restrict__ src,
                               const float* __restrict__ ea,
                               int* __restrict__ s_src, float* __restrict__ ea_r, int E){
  int i = blockIdx.x*256 + threadIdx.x;
  if (i >= E) return;
  int eid = s_eid[i];
  s_src[i] = src[eid];
  const float* a = ea + (size_t)eid*FBOND;
  float* o = ea_r + (size_t)i*12;
  #pragma unroll
  for (int k=0;k<FBOND;k++) o[k] = a[k];
  o[11] = 0.f;
}

// ---------------- GINE message + aggregate (fp32 h -> split-bf16 z) ----------------
// per-lane bond-W rows hoisted to registers; 2-deep software pipeline on edges.
template<bool RE>
__global__ void gine_msg_kernel(const float* __restrict__ h, const float* __restrict__ ea,
                                const float* __restrict__ bW, const float* __restrict__ bb,
                                const int* __restrict__ src, const int* __restrict__ s_eid,
                                const int* __restrict__ s_src, const float* __restrict__ ea_r,
                                const int* __restrict__ row_ptr, const float* __restrict__ eps,
                                int layer, short* __restrict__ zh, short* __restrict__ zl){
  int t = threadIdx.x;
  int node = (blockIdx.x*256 + t) >> 6;
  int lane = t & 63;
  if (node >= N_NODES) return;
  int c0 = lane*4;
  float4 w[FBOND];
  #pragma unroll
  for (int k=0;k<FBOND;k++) w[k] = *(const float4*)&bW[k*HDIM + c0];
  float4 bb4 = *(const float4*)&bb[c0];
  float4 hv = *(const float4*)&h[(size_t)node*HDIM + c0];
  float epsf = 1.0f + eps[layer];
  float ax = hv.x*epsf, ay = hv.y*epsf, az = hv.z*epsf, aw = hv.w*epsf;
  int s = row_ptr[node], e = row_ptr[node+1];

  float4 hc = make_float4(0,0,0,0), e0 = hc, e1 = hc, e2 = hc;
  if (s < e){
    if (RE){
      hc = *(const float4*)&h[(size_t)s_src[s]*HDIM + c0];
      const float4* ep = (const float4*)(ea_r + (size_t)s*12);
      e0 = ep[0]; e1 = ep[1]; e2 = ep[2];
    } else {
      int eid = s_eid[s];
      hc = *(const float4*)&h[(size_t)src[eid]*HDIM + c0];
      const float* er = ea + (size_t)eid*FBOND;
      e0 = make_float4(er[0],er[1],er[2],er[3]);
      e1 = make_float4(er[4],er[5],er[6],er[7]);
      e2 = make_float4(er[8],er[9],er[10],0.f);
    }
  }
  for (int idx=s; idx<e; idx++){
    float4 hn = hc, f0 = e0, f1 = e1, f2 = e2;
    if (idx+1 < e){
      if (RE){
        hn = *(const float4*)&h[(size_t)s_src[idx+1]*HDIM + c0];
        const float4* ep = (const float4*)(ea_r + (size_t)(idx+1)*12);
        f0 = ep[0]; f1 = ep[1]; f2 = ep[2];
      } else {
        int eid = s_eid[idx+1];
        hn = *(const float4*)&h[(size_t)src[eid]*HDIM + c0];
        const float* er = ea + (size_t)eid*FBOND;
        f0 = make_float4(er[0],er[1],er[2],er[3]);
        f1 = make_float4(er[4],er[5],er[6],er[7]);
        f2 = make_float4(er[8],er[9],er[10],0.f);
      }
    }
    float ex = bb4.x, ey = bb4.y, ez = bb4.z, ew = bb4.w;
    float ek[FBOND] = {e0.x,e0.y,e0.z,e0.w, e1.x,e1.y,e1.z,e1.w, e2.x,e2.y,e2.z};
    #pragma unroll
    for (int k=0;k<FBOND;k++){
      ex += ek[k]*w[k].x; ey += ek[k]*w[k].y; ez += ek[k]*w[k].z; ew += ek[k]*w[k].w;
    }
    ax += fmaxf(hc.x+ex, 0.f);
    ay += fmaxf(hc.y+ey, 0.f);
    az += fmaxf(hc.z+ez, 0.f);
    aw += fmaxf(hc.w+ew, 0.f);
    hc = hn; e0 = f0; e1 = f1; e2 = f2;
  }
  short4 oh, ol;
  oh.x=f2bf(ax); ol.x=f2bf(ax-bf2f(oh.x));
  oh.y=f2bf(ay); ol.y=f2bf(ay-bf2f(oh.y));
  oh.z=f2bf(az); ol.z=f2bf(az-bf2f(oh.z));
  oh.w=f2bf(aw); ol.w=f2bf(aw-bf2f(oh.w));
  *(short4*)&zh[(size_t)node*HDIM + c0] = oh;
  *(short4*)&zl[(size_t)node*HDIM + c0] = ol;
}

// ---------------- pack weights into MFMA B-fragment layout, split hi/lo -------------
__global__ void packB_kernel(const float* __restrict__ B, short* __restrict__ Bph,
                             short* __restrict__ Bpl, int K, int N){
  int idx = blockIdx.x*256 + threadIdx.x;
  if (idx >= K*N) return;
  int b    = idx & 7;
  int lane = (idx >> 3) & 63;
  int t2   = idx >> 9;
  int KT   = K >> 5;
  int kt   = t2 % KT, nt = t2 / KT;
  int k = kt*32 + ((lane>>4)<<3) + b;
  int n = nt*16 + (lane&15);
  float w = B[(size_t)k*N + n];
  short hi = f2bf(w);
  Bph[idx] = hi;
  Bpl[idx] = f2bf(w - bf2f(hi));
}

// ---------------- pack LSTM [Wih|Whh]^T (K=768, N=1024) + bias, split hi/lo --------
__global__ void packWcat_kernel(const float* __restrict__ Wih, const float* __restrict__ Whh,
                                const float* __restrict__ bih, const float* __restrict__ bhh,
                                short* __restrict__ Wch, short* __restrict__ Wcl,
                                float* __restrict__ bias_c){
  int idx = blockIdx.x*256 + threadIdx.x;
  if (idx < 1024) bias_c[idx] = bih[idx] + bhh[idx];
  if (idx >= 768*1024) return;
  int b    = idx & 7;
  int lane = (idx >> 3) & 63;
  int t2   = idx >> 9;
  const int KT = 24;
  int kt   = t2 % KT, nt = t2 / KT;
  int k = kt*32 + ((lane>>4)<<3) + b;
  int n = nt*16 + (lane&15);
  float w = (k < 512) ? Wih[(size_t)n*512 + k] : Whh[(size_t)n*256 + (k-512)];
  short hi = f2bf(w);
  Wch[idx] = hi;
  Wcl[idx] = f2bf(w - bf2f(hi));
}

// ---------------- fused GINE MLP: h += relu(bn2(relu(bn1(z@W1)) @ W2)) ----------------
// one block = 64 rows, 8 waves. c1 lives only in LDS (split bf16, stride 520).
__launch_bounds__(512)
__global__ void gine_mlp_fused(const short* __restrict__ Ah, const short* __restrict__ Al,
                               const short* __restrict__ B1h, const short* __restrict__ B1l,
                               const short* __restrict__ B2h, const short* __restrict__ B2l,
                               const float* __restrict__ sc1v, const float* __restrict__ sh1v,
                               const float* __restrict__ sc2v, const float* __restrict__ sh2v,
                               float* __restrict__ hio){
  __shared__ short smem[66560];        // 133.1 KB
  short* sAh  = smem;                  // [64][264]
  short* sAl  = smem + 16896;
  short* sC1h = smem;                  // [64][520] (aliases A after barrier)
  short* sC1l = smem + 33280;
  int t = threadIdx.x;
  int lane = t & 63, wid = t >> 6;
  int lrow = lane & 15, lk8 = (lane>>4)<<3, drow0 = (lane>>4)<<2;
  int m0 = blockIdx.x * 64;

  // ---- stage A = z[m0..m0+64) x 256, split hi/lo ----
  {
    int row = t >> 3, c8 = t & 7;
    int grow = min(m0 + row, N_NODES-1);
    const short* gh = Ah + (size_t)grow*HDIM + c8*8;
    const short* gl = Al + (size_t)grow*HDIM + c8*8;
    #pragma unroll
    for (int i=0;i<4;i++){
      *(s8v*)&sAh[row*264 + i*64 + c8*8] = *(const s8v*)(gh + i*64);
      *(s8v*)&sAl[row*264 + i*64 + c8*8] = *(const s8v*)(gl + i*64);
    }
  }
  __syncthreads();

  // ---- GEMM1: wave wid computes c1 cols [wid*64, wid*64+64), K=256 ----
  f32x4 acc1[4][4];
  #pragma unroll
  for (int i=0;i<4;i++)
    #pragma unroll
    for (int j=0;j<4;j++) acc1[i][j] = (f32x4){0.f,0.f,0.f,0.f};
  size_t b1base = (size_t)wid*16384 + lane*8;          // nt = wid*4+nf, KT=8
  for (int kt=0; kt<8; ++kt){
    s8v bh[4], bl[4];
    #pragma unroll
    for (int nf=0;nf<4;nf++){
      size_t o = b1base + ((size_t)nf*8 + kt)*512;
      bh[nf] = *(const s8v*)(B1h + o);
      bl[nf] = *(const s8v*)(B1l + o);
    }
    #pragma unroll
    for (int mf=0;mf<4;mf++){
      int rsh = (mf*16 + lrow)*264 + kt*32 + lk8;
      s8v ah = *(const s8v*)&sAh[rsh];
      s8v al = *(const s8v*)&sAl[rsh];
      #pragma unroll
      for (int nf=0;nf<4;nf++){
        acc1[mf][nf] = __builtin_amdgcn_mfma_f32_16x16x32_bf16(ah, bh[nf], acc1[mf][nf],0,0,0);
        acc1[mf][nf] = __builtin_amdgcn_mfma_f32_16x16x32_bf16(ah, bl[nf], acc1[mf][nf],0,0,0);
        acc1[mf][nf] = __builtin_amdgcn_mfma_f32_16x16x32_bf16(al, bh[nf], acc1[mf][nf],0,0,0);
      }
    }
  }
  __syncthreads();   // all waves done reading A

  // ---- write c1 = relu(bn1(.)) split into LDS ----
  #pragma unroll
  for (int nf=0;nf<4;nf++){
    int col = wid*64 + nf*16 + lrow;
    float scv = sc1v[col], shv = sh1v[col];
    #pragma unroll
    for (int mf=0;mf<4;mf++){
      int row = mf*16 + drow0;
      #pragma unroll
      for (int r=0;r<4;r++){
        float v = fmaxf(acc1[mf][nf][r]*scv + shv, 0.f);
        short hi = f2bf(v);
        sC1h[(row+r)*520 + col] = hi;
        sC1l[(row+r)*520 + col] = f2bf(v - bf2f(hi));
      }
    }
  }
  __syncthreads();

  // ---- GEMM2: wave wid computes out cols [wid*32, +32), K=512 ----
  f32x4 acc2[4][2];
  #pragma unroll
  for (int i=0;i<4;i++)
    #pragma unroll
    for (int j=0;j<2;j++) acc2[i][j] = (f32x4){0.f,0.f,0.f,0.f};
  size_t b2base = (size_t)wid*16384 + lane*8;          // nt2 = wid*2+nf, KT2=16
  for (int kt=0; kt<16; ++kt){
    size_t o0 = b2base + (size_t)kt*512;
    size_t o1 = b2base + (size_t)(16+kt)*512;
    s8v bh0 = *(const s8v*)(B2h + o0);
    s8v bl0 = *(const s8v*)(B2l + o0);
    s8v bh1 = *(const s8v*)(B2h + o1);
    s8v bl1 = *(const s8v*)(B2l + o1);
    #pragma unroll
    for (int mf=0;mf<4;mf++){
      int rsh = (mf*16 + lrow)*520 + kt*32 + lk8;
      s8v ah = *(const s8v*)&sC1h[rsh];
      s8v al = *(const s8v*)&sC1l[rsh];
      acc2[mf][0] = __builtin_amdgcn_mfma_f32_16x16x32_bf16(ah, bh0, acc2[mf][0],0,0,0);
      acc2[mf][0] = __builtin_amdgcn_mfma_f32_16x16x32_bf16(ah, bl0, acc2[mf][0],0,0,0);
      acc2[mf][0] = __builtin_amdgcn_mfma_f32_16x16x32_bf16(al, bh0, acc2[mf][0],0,0,0);
      acc2[mf][1] = __builtin_amdgcn_mfma_f32_16x16x32_bf16(ah, bh1, acc2[mf][1],0,0,0);
      acc2[mf][1] = __builtin_amdgcn_mfma_f32_16x16x32_bf16(ah, bl1, acc2[mf][1],0,0,0);
      acc2[mf][1] = __builtin_amdgcn_mfma_f32_16x16x32_bf16(al, bh1, acc2[mf][1],0,0,0);
    }
  }

  // ---- epilogue: h += relu(bn2(.)) ----
  #pragma unroll
  for (int nf=0;nf<2;nf++){
    int col = wid*32 + nf*16 + lrow;
    float scv = sc2v[col], shv = sh2v[col];
    #pragma unroll
    for (int mf=0;mf<4;mf++){
      #pragma unroll
      for (int r=0;r<4;r++){
        int row = m0 + mf*16 + drow0 + r;
        if (row < N_NODES){
          size_t o = (size_t)row*HDIM + col;
          hio[o] = fmaxf(acc2[mf][nf][r]*scv + shv, 0.f) + hio[o];
        }
      }
    }
  }
}

// ---------------- split-bf16 MFMA GEMM (LSTM gates), LDS-staged A ----------------
__launch_bounds__(256)
__global__ void gemm_mfma0(const short* __restrict__ Ah, const short* __restrict__ Al,
                           const short* __restrict__ Bh, const short* __restrict__ Bl,
                           int M, int N, int K,
                           const float* __restrict__ sh, float* __restrict__ Cf){
  __shared__ short As[2][2][64*72];
  int t    = threadIdx.x;
  int lane = t & 63;
  int wid  = t >> 6;
  int m0 = blockIdx.y * 64;
  int n0 = blockIdx.x * 128 + wid * 32;
  int lrow = lane & 15;
  int lk8  = (lane >> 4) << 3;
  int KT = K >> 5;
  int NT = K >> 6;

  f32x4 acc[4][2];
  #pragma unroll
  for (int i=0;i<4;i++)
    #pragma unroll
    for (int j=0;j<2;j++) acc[i][j] = (f32x4){0.f,0.f,0.f,0.f};

  int r0 = t >> 3, c8 = t & 7;
  int gr0 = min(m0 + r0,      M-1);
  int gr1 = min(m0 + r0 + 32, M-1);
  const short* pa0h = Ah + (size_t)gr0*K + c8*8;
  const short* pa0l = Al + (size_t)gr0*K + c8*8;
  const short* pa1h = Ah + (size_t)gr1*K + c8*8;
  const short* pa1l = Al + (size_t)gr1*K + c8*8;
  int wsh0 = r0*72 + c8*8;
  int wsh1 = (r0+32)*72 + c8*8;

  size_t boff = ((size_t)(n0 >> 4) * KT) * 512 + lane*8;

  s8v vh0 = *(const s8v*)(pa0h);
  s8v vh1 = *(const s8v*)(pa1h);
  s8v vl0 = *(const s8v*)(pa0l);
  s8v vl1 = *(const s8v*)(pa1l);
  *(s8v*)&As[0][0][wsh0] = vh0;  *(s8v*)&As[0][0][wsh1] = vh1;
  *(s8v*)&As[0][1][wsh0] = vl0;  *(s8v*)&As[0][1][wsh1] = vl1;
  __syncthreads();

  for (int st=0; st<NT; ++st){
    int cur = st & 1;
    if (st+1 < NT){
      int ko = (st+1)*64;
      vh0 = *(const s8v*)(pa0h + ko);
      vh1 = *(const s8v*)(pa1h + ko);
      vl0 = *(const s8v*)(pa0l + ko);
      vl1 = *(const s8v*)(pa1l + ko);
    }
    #pragma unroll
    for (int ktl=0; ktl<2; ++ktl){
      int kt = st*2 + ktl;
      s8v bh0 = *(const s8v*)(Bh + boff + (size_t)kt*512);
      s8v bl0 = *(const s8v*)(Bl + boff + (size_t)kt*512);
      s8v bh1 = *(const s8v*)(Bh + boff + (size_t)(KT + kt)*512);
      s8v bl1 = *(const s8v*)(Bl + boff + (size_t)(KT + kt)*512);
      int ksh = ktl*32 + lk8;
      #pragma unroll
      for (int mf=0; mf<4; ++mf){
        int rsh = (mf*16 + lrow)*72 + ksh;
        s8v ah = *(const s8v*)&As[cur][0][rsh];
        s8v al = *(const s8v*)&As[cur][1][rsh];
        acc[mf][0] = __builtin_amdgcn_mfma_f32_16x16x32_bf16(ah, bh0, acc[mf][0], 0,0,0);
        acc[mf][0] = __builtin_amdgcn_mfma_f32_16x16x32_bf16(ah, bl0, acc[mf][0], 0,0,0);
        acc[mf][0] = __builtin_amdgcn_mfma_f32_16x16x32_bf16(al, bh0, acc[mf][0], 0,0,0);
        acc[mf][1] = __builtin_amdgcn_mfma_f32_16x16x32_bf16(ah, bh1, acc[mf][1], 0,0,0);
        acc[mf][1] = __builtin_amdgcn_mfma_f32_16x16x32_bf16(ah, bl1, acc[mf][1], 0,0,0);
        acc[mf][1] = __builtin_amdgcn_mfma_f32_16x16x32_bf16(al, bh1, acc[mf][1], 0,0,0);
      }
    }
    if (st+1 < NT){
      int nxt = cur ^ 1;
      *(s8v*)&As[nxt][0][wsh0] = vh0;  *(s8v*)&As[nxt][0][wsh1] = vh1;
      *(s8v*)&As[nxt][1][wsh0] = vl0;  *(s8v*)&As[nxt][1][wsh1] = vl1;
    }
    __syncthreads();
  }

  int drow0 = (lane >> 4) * 4;
  #pragma unroll
  for (int nf=0; nf<2; nf++){
    int col = n0 + nf*16 + lrow;
    float shv = sh[col];
    #pragma unroll
    for (int mf=0; mf<4; mf++){
      #pragma unroll
      for (int r=0; r<4; r++){
        int row = m0 + mf*16 + drow0 + r;
        if (row < M) Cf[(size_t)row*N + col] = acc[mf][nf][r] + shv;
      }
    }
  }
}

// ---------------- BN fold ----------------
__global__ void fold_kernel(
  const float* __restrict__ b1,  const float* __restrict__ g1,  const float* __restrict__ bb1,
  const float* __restrict__ m1,  const float* __restrict__ v1,
  const float* __restrict__ b2,  const float* __restrict__ g2,  const float* __restrict__ bb2,
  const float* __restrict__ m2,  const float* __restrict__ v2,
  const float* __restrict__ cb1, const float* __restrict__ cg1, const float* __restrict__ cbb1,
  const float* __restrict__ cm1, const float* __restrict__ cv1,
  const float* __restrict__ cb2, const float* __restrict__ cg2, const float* __restrict__ cbb2,
  const float* __restrict__ cm2, const float* __restrict__ cv2,
  float* __restrict__ sc1, float* __restrict__ sh1,
  float* __restrict__ sc2, float* __restrict__ sh2,
  float* __restrict__ csc1, float* __restrict__ csh1,
  float* __restrict__ csc2, float* __restrict__ csh2){
  int idx = blockIdx.x*256 + threadIdx.x;
  const int n1 = NLAY*512, n2 = NLAY*256;
  if (idx < n1){
    float s = g1[idx]*rsqrtf(v1[idx]+1e-5f);
    sc1[idx]=s; sh1[idx]=(b1[idx]-m1[idx])*s + bb1[idx];
  } else if (idx < n1+n2){
    int i = idx-n1;
    float s = g2[i]*rsqrtf(v2[i]+1e-5f);
    sc2[i]=s; sh2[i]=(b2[i]-m2[i])*s + bb2[i];
  } else if (idx < n1+n2+256){
    int i = idx-n1-n2;
    float s = cg1[i]*rsqrtf(cv1[i]+1e-5f);
    csc1[i]=s; csh1[i]=(cb1[i]-cm1[i])*s + cbb1[i];
  } else if (idx < n1+n2+256+128){
    int i = idx-n1-n2-256;
    float s = cg2[i]*rsqrtf(cv2[i]+1e-5f);
    csc2[i]=s; csh2[i]=(cb2[i]-cm2[i])*s + cbb2[i];
  }
}

// ---------------- LSTM pointwise (writes q/hst fp32 + split) ----------------
__global__ void lstm_kernel(const float* __restrict__ gates, float* __restrict__ cst,
                            float* __restrict__ qs, short* __restrict__ qsh,
                            short* __restrict__ qsl){
  int idx = blockIdx.x*256 + threadIdx.x;
  int b = idx >> 8, j = idx & 255;
  const float* g = &gates[(size_t)b*1024];
  float ig = sigmoidf_(g[j]);
  float fg = sigmoidf_(g[j+256]);
  float gg = tanhf(g[j+512]);
  float og = sigmoidf_(g[j+768]);
  float c  = fg*cst[idx] + ig*gg;
  float hv = og*tanhf(c);
  cst[idx] = c;
  size_t base = (size_t)b*768;
  qs[base + j]       = hv;
  qs[base + 512 + j] = hv;
  short hi = f2bf(hv);
  short lo = f2bf(hv - bf2f(hi));
  qsh[base + j] = hi;        qsl[base + j] = lo;
  qsh[base + 512 + j] = hi;  qsl[base + 512 + j] = lo;
}

// ---------------- fused attention: ener + segment softmax + weighted r ----------------
__global__ void attn_fused_kernel(const float* __restrict__ h, float* __restrict__ qs,
                                  short* __restrict__ qsh, short* __restrict__ qsl,
                                  const int* __restrict__ segs){
  __shared__ float en[CK];
  __shared__ float red[256];
  __shared__ float hstS[HDIM];
  int g = blockIdx.x, t = threadIdx.x;
  int s = segs[g], e = segs[g+1];
  int lane = t & 63, w = t >> 6;
  if (t < HDIM) hstS[t] = qs[(size_t)g*768 + 512 + t];
  __syncthreads();
  float4 hq = *(const float4*)&hstS[lane*4];
  float m_run = -INFINITY, s_run = 0.f, racc = 0.f;
  for (int base = s; base < e; base += CK){
    int cnt = min(e - base, CK);
    for (int li = w; li < cnt; li += 4){
      float4 hv = *(const float4*)&h[(size_t)(base+li)*HDIM + lane*4];
      float v = hv.x*hq.x + hv.y*hq.y + hv.z*hq.z + hv.w*hq.w;
      for (int o=32; o; o>>=1) v += __shfl_down(v, o);
      if (lane==0) en[li] = v;
    }
    __syncthreads();
    red[t] = (t < cnt) ? en[t] : -INFINITY;
    __syncthreads();
    for (int o=128;o>0;o>>=1){ if (t<o) red[t]=fmaxf(red[t],red[t+o]); __syncthreads(); }
    float nm = fmaxf(m_run, red[0]);
    __syncthreads();
    float ce = (t < cnt) ? expf(en[t]-nm) : 0.f;
    red[t] = ce; __syncthreads();
    for (int o=128;o>0;o>>=1){ if (t<o) red[t]+=red[t+o]; __syncthreads(); }
    float csum = red[0];
    __syncthreads();
    if (t < cnt) en[t] = ce;
    __syncthreads();
    float scale = (m_run == -INFINITY) ? 0.f : expf(m_run - nm);
    s_run = s_run*scale + csum;
    racc  = racc*scale;
    for (int j=0;j<cnt;j++)
      racc += en[j] * h[(size_t)(base+j)*HDIM + t];
    m_run = nm;
    __syncthreads();
  }
  float r = racc / (s_run + 1e-16f);
  size_t o = (size_t)g*768 + 256 + t;
  qs[o] = r;
  short hi = f2bf(r);
  qsh[o] = hi;
  qsl[o] = f2bf(r - bf2f(hi));
}

// ---------------- fused classifier ----------------
__global__ void classifier_kernel(const float* __restrict__ qs,
   const float* __restrict__ cW1, const float* __restrict__ csc1, const float* __restrict__ csh1,
   const float* __restrict__ cW2, const float* __restrict__ csc2, const float* __restrict__ csh2,
   const float* __restrict__ cW3, const float* __restrict__ cb3, float* __restrict__ out){
  __shared__ float sq[512];
  __shared__ float so1[256];
  __shared__ float so2[128];
  __shared__ float fr[256];
  int g = blockIdx.x, t = threadIdx.x;
  sq[t]     = qs[(size_t)g*768 + t];
  sq[t+256] = qs[(size_t)g*768 + 256 + t];
  __syncthreads();
  float acc = 0.f;
  for (int k=0;k<512;k++) acc += sq[k]*cW1[(size_t)k*256 + t];
  so1[t] = fmaxf(acc*csc1[t]+csh1[t], 0.f);
  __syncthreads();
  if (t < 128){
    float a2 = 0.f;
    for (int k=0;k<256;k++) a2 += so1[k]*cW2[(size_t)k*128 + t];
    so2[t] = fmaxf(a2*csc2[t]+csh2[t], 0.f);
  }
  __syncthreads();
  fr[t] = (t<128) ? so2[t]*cW3[t] : 0.f;
  __syncthreads();
  for (int o=128;o>0;o>>=1){ if (t<o) fr[t]+=fr[t+o]; __syncthreads(); }
  if (t==0) out[g] = fr[0] + cb3[0];
}

// ---------------- host ----------------
extern "C" void kernel_launch(void* const* d_in, const int* in_sizes, int n_in,
                              void* d_out, int out_size, void* d_ws, size_t ws_size,
                              hipStream_t stream){
  const float* x         = (const float*)d_in[0];
  const float* edge_attr = (const float*)d_in[1];
  const int*   edge_idx  = (const int*)  d_in[2];
  const int*   batch     = (const int*)  d_in[3];
  const float* atom_W    = (const float*)d_in[4];
  const float* atom_b    = (const float*)d_in[5];
  const float* bond_W    = (const float*)d_in[6];
  const float* bond_b    = (const float*)d_in[7];
  const float* eps       = (const float*)d_in[8];
  const float* W1        = (const float*)d_in[9];
  const float* b1        = (const float*)d_in[10];
  const float* bn1_g     = (const float*)d_in[11];
  const float* bn1_b     = (const float*)d_in[12];
  const float* bn1_m     = (const float*)d_in[13];
  const float* bn1_v     = (const float*)d_in[14];
  const float* W2        = (const float*)d_in[15];
  const float* b2        = (const float*)d_in[16];
  const float* bn_g      = (const float*)d_in[17];
  const float* bn_b      = (const float*)d_in[18];
  const float* bn_m      = (const float*)d_in[19];
  const float* bn_v      = (const float*)d_in[20];
  const float* lstm_Wih  = (const float*)d_in[21];
  const float* lstm_Whh  = (const float*)d_in[22];
  const float* lstm_bih  = (const float*)d_in[23];
  const float* lstm_bhh  = (const float*)d_in[24];
  const float* cW1       = (const float*)d_in[25];
  const float* cb1       = (const float*)d_in[26];
  const float* cbn1_g    = (const float*)d_in[27];
  const float* cbn1_b    = (const float*)d_in[28];
  const float* cbn1_m    = (const float*)d_in[29];
  const float* cbn1_v    = (const float*)d_in[30];
  const float* cW2       = (const float*)d_in[31];
  const float* cb2       = (const float*)d_in[32];
  const float* cbn2_g    = (const float*)d_in[33];
  const float* cbn2_b    = (const float*)d_in[34];
  const float* cbn2_m    = (const float*)d_in[35];
  const float* cbn2_v    = (const float*)d_in[36];
  const float* cW3       = (const float*)d_in[37];
  const float* cb3       = (const float*)d_in[38];

  const int* src = edge_idx;
  const int* dst = edge_idx + N_EDGES;

  char* ws = (char*)d_ws;
  size_t off = 0;
  auto alloc = [&](size_t bytes)->void*{
    void* p = ws + off; off += (bytes + 255) & ~(size_t)255; return p;
  };
  float* h       = (float*)alloc((size_t)N_NODES*HDIM*4);     // 102.4 MB fp32 master
  short* zh      = (short*)alloc((size_t)N_NODES*HDIM*2);     //  51.2 MB
  short* zl      = (short*)alloc((size_t)N_NODES*HDIM*2);     //  51.2 MB
  int*   row_ptr = (int*)  alloc((size_t)(N_NODES+1)*4);
  int*   cursor  = (int*)  alloc((size_t)N_NODES*4);
  int*   s_eid   = (int*)  alloc((size_t)N_EDGES*4);
  int*   segs    = (int*)  alloc((size_t)(NB+1)*4);
  short* W1ph    = (short*)alloc((size_t)NLAY*HDIM*2*HDIM*2);
  short* W1pl    = (short*)alloc((size_t)NLAY*HDIM*2*HDIM*2);
  short* W2ph    = (short*)alloc((size_t)NLAY*HDIM*2*HDIM*2);
  short* W2pl    = (short*)alloc((size_t)NLAY*HDIM*2*HDIM*2);
  float* sc1     = (float*)alloc(NLAY*512*4);
  float* sh1     = (float*)alloc(NLAY*512*4);
  float* sc2     = (float*)alloc(NLAY*256*4);
  float* sh2     = (float*)alloc(NLAY*256*4);
  float* csc1    = (float*)alloc(256*4);
  float* csh1    = (float*)alloc(256*4);
  float* csc2    = (float*)alloc(128*4);
  float* csh2    = (float*)alloc(128*4);

  if (off >= ws_size){
    sentinel_kernel<<<(out_size+255)/256, 256, 0, stream>>>((float*)d_out, out_size);
    return;
  }
  size_t remain = ws_size - off;

  // optional edge reorder buffers (20.8 MB)
  const size_t RE_BYTES = (((size_t)N_EDGES*4 + 255)&~(size_t)255)
                        + (((size_t)N_EDGES*12*4 + 255)&~(size_t)255);
  bool use_re = (remain >= RE_BYTES);
  int*   s_src = nullptr;
  float* ea_r  = nullptr;
  if (use_re){
    s_src = (int*)  alloc((size_t)N_EDGES*4);
    ea_r  = (float*)alloc((size_t)N_EDGES*12*4);
  }

  // Set2Set scratch aliases zh (dead after last fused GEMM).
  char*  zb      = (char*)(void*)zh;
  float* gates   = (float*)zb;                          // 16.78 MB
  float* qs      = (float*)(zb + 16777216);             // 12.58 MB
  float* cst     = (float*)(zb + 29360128);             //  4.19 MB
  short* qsh     = (short*)(zb + 33554432);             //  6.29 MB
  short* qsl     = (short*)(zb + 39845888);             //  6.29 MB
  short* Wch     = (short*)(zb + 46137344);             //  1.57 MB
  short* Wcl     = (short*)(zb + 47710208);             //  1.57 MB
  float* bias_c  = (float*)(zb + 49283072);             //  4 KB

  // ---- prep: fold BN+bias, pack GNN weights (split hi/lo) ----
  fold_kernel<<<(NLAY*512+NLAY*256+256+128+255)/256, 256, 0, stream>>>(
      b1, bn1_g, bn1_b, bn1_m, bn1_v,
      b2, bn_g,  bn_b,  bn_m,  bn_v,
      cb1, cbn1_g, cbn1_b, cbn1_m, cbn1_v,
      cb2, cbn2_g, cbn2_b, cbn2_m, cbn2_v,
      sc1, sh1, sc2, sh2, csc1, csh1, csc2, csh2);
  for (int l=0; l<NLAY; l++){
    packB_kernel<<<(HDIM*2*HDIM)/256, 256, 0, stream>>>(
        W1 + (size_t)l*HDIM*2*HDIM, W1ph + (size_t)l*HDIM*2*HDIM, W1pl + (size_t)l*HDIM*2*HDIM, HDIM, 2*HDIM);
    packB_kernel<<<(HDIM*2*HDIM)/256, 256, 0, stream>>>(
        W2 + (size_t)l*HDIM*2*HDIM, W2ph + (size_t)l*HDIM*2*HDIM, W2pl + (size_t)l*HDIM*2*HDIM, 2*HDIM, HDIM);
  }

  // ---- embeddings ----
  atom_embed_kernel<<<N_NODES/8, 256, 0, stream>>>(x, atom_W, atom_b, h);

  // ---- CSR by dst + batch segment starts (+ optional edge reorder) ----
  hipMemsetAsync(cursor, 0, (size_t)N_NODES*4, stream);
  count_kernel<<<(N_EDGES+255)/256, 256, 0, stream>>>(dst, cursor, N_EDGES);
  scan_kernel<<<1, 1024, 0, stream>>>(cursor, row_ptr, N_NODES);
  hipMemcpyAsync(cursor, row_ptr, (size_t)N_NODES*4, hipMemcpyDeviceToDevice, stream);
  fill_kernel<<<(N_EDGES+255)/256, 256, 0, stream>>>(dst, cursor, s_eid, N_EDGES);
  segstart_kernel<<<(NB+256)/256, 256, 0, stream>>>(batch, segs, N_NODES, NB);
  if (use_re)
    reorder_kernel<<<(N_EDGES+255)/256, 256, 0, stream>>>(s_eid, src, edge_attr, s_src, ea_r, N_EDGES);

  // ---- GINE layers: message pass + fused 2-GEMM MLP ----
  int gx = (N_NODES + 63)/64;
  for (int l=0; l<NLAY; l++){
    if (use_re)
      gine_msg_kernel<true><<<N_NODES/4, 256, 0, stream>>>(h, edge_attr, bond_W, bond_b,
          src, s_eid, s_src, ea_r, row_ptr, eps, l, zh, zl);
    else
      gine_msg_kernel<false><<<N_NODES/4, 256, 0, stream>>>(h, edge_attr, bond_W, bond_b,
          src, s_eid, s_src, ea_r, row_ptr, eps, l, zh, zl);
    gine_mlp_fused<<<gx, 512, 0, stream>>>(
        zh, zl,
        W1ph + (size_t)l*HDIM*2*HDIM, W1pl + (size_t)l*HDIM*2*HDIM,
        W2ph + (size_t)l*HDIM*2*HDIM, W2pl + (size_t)l*HDIM*2*HDIM,
        sc1 + l*512, sh1 + l*512, sc2 + l*256, sh2 + l*256, h);
  }

  // ---- Set2Set (scratch aliases zh, now dead) ----
  packWcat_kernel<<<(768*1024+255)/256, 256, 0, stream>>>(lstm_Wih, lstm_Whh, lstm_bih, lstm_bhh,
                                                          Wch, Wcl, bias_c);
  hipMemsetAsync(qsh, 0, (size_t)NB*768*2, stream);
  hipMemsetAsync(qsl, 0, (size_t)NB*768*2, stream);
  hipMemsetAsync(cst, 0, (size_t)NB*HDIM*4, stream);
  for (int sstep=0; sstep<3; sstep++){
    gemm_mfma0<<<dim3(1024/128, NB/64), 256, 0, stream>>>(
        qsh, qsl, Wch, Wcl, NB, 1024, 768, bias_c, gates);
    lstm_kernel<<<(NB*HDIM)/256, 256, 0, stream>>>(gates, cst, qs, qsh, qsl);
    attn_fused_kernel<<<NB, 256, 0, stream>>>(h, qs, qsh, qsl, segs);
  }

  // ---- classifier ----
  classifier_kernel<<<NB, 256, 0, stream>>>(qs, cW1, csc1, csh1, cW2, csc2, csh2,
                                            cW3, cb3, (float*)d_out);
}

// Round 10
// 2106.410 us; speedup vs baseline: 2.2803x; 1.1347x over previous
//
#include <hip/hip_runtime.h>
#include <hip/hip_bf16.h>

#define N_NODES 100000
#define N_EDGES 400000
#define NB      4096
#define FAT     30
#define FBOND   11
#define HDIM    256
#define NLAY    5
#define CK      128

typedef short s8v  __attribute__((ext_vector_type(8)));
typedef float f32x4 __attribute__((ext_vector_type(4)));

static __device__ __forceinline__ float sigmoidf_(float x){ return 1.0f/(1.0f+expf(-x)); }
static __device__ __forceinline__ float bf2f(short s){
  return __uint_as_float(((unsigned)(unsigned short)s) << 16);
}
static __device__ __forceinline__ short f2bf(float f){   // RNE
  unsigned u = __float_as_uint(f);
  u += 0x7fffu + ((u >> 16) & 1u);
  return (short)(u >> 16);
}

// ---------------- sentinel (ws too small diagnostic) ----------------
__global__ void sentinel_kernel(float* out, int n){
  int i = blockIdx.x*256 + threadIdx.x;
  if (i < n) out[i] = 12345.0f;
}

// ---------------- atom embedding: h = x @ atom_W + atom_b (fp32) ----------------
__global__ void atom_embed_kernel(const float* __restrict__ x, const float* __restrict__ W,
                                  const float* __restrict__ b, float* __restrict__ h){
  __shared__ float xs[8][FAT];
  int n0 = blockIdx.x * 8;
  int t = threadIdx.x;
  if (t < 8*FAT) xs[t/FAT][t%FAT] = x[(size_t)(n0 + t/FAT)*FAT + t%FAT];
  __syncthreads();
  int c = t;
  float acc[8];
  float bias = b[c];
  #pragma unroll
  for (int r=0;r<8;r++) acc[r]=bias;
  #pragma unroll
  for (int k=0;k<FAT;k++){
    float w = W[k*HDIM + c];
    #pragma unroll
    for (int r=0;r<8;r++) acc[r] += xs[r][k]*w;
  }
  #pragma unroll
  for (int r=0;r<8;r++) h[(size_t)(n0+r)*HDIM + c] = acc[r];
}

// ---------------- CSR build over dst ----------------
__global__ void count_kernel(const int* __restrict__ dst, int* __restrict__ counts, int E){
  int e = blockIdx.x*blockDim.x + threadIdx.x;
  if (e < E) atomicAdd(&counts[dst[e]], 1);
}

__global__ void scan_kernel(const int* __restrict__ counts, int* __restrict__ row_ptr, int n){
  __shared__ int part[1024];
  int t = threadIdx.x;
  int chunk = (n + 1023) >> 10;
  int s = t*chunk, e2 = min(s+chunk, n);
  int sum = 0;
  for (int i=s;i<e2;i++) sum += counts[i];
  part[t] = sum; __syncthreads();
  for (int off=1; off<1024; off<<=1){
    int v = (t>=off) ? part[t-off] : 0;
    __syncthreads();
    part[t] += v;
    __syncthreads();
  }
  int run = part[t]-sum;
  for (int i=s;i<e2;i++){ row_ptr[i]=run; run+=counts[i]; }
  if (e2==n && s<=n) row_ptr[n]=run;
}

__global__ void fill_kernel(const int* __restrict__ dst, int* __restrict__ cursor,
                            int* __restrict__ sorted_eid, int E){
  int e = blockIdx.x*blockDim.x + threadIdx.x;
  if (e < E){ int pos = atomicAdd(&cursor[dst[e]],1); sorted_eid[pos]=e; }
}

__global__ void segstart_kernel(const int* __restrict__ batch, int* __restrict__ segs, int n, int nb){
  int g = blockIdx.x*blockDim.x + threadIdx.x;
  if (g > nb) return;
  int lo=0, hi=n;
  while (lo<hi){ int mid=(lo+hi)>>1; if (batch[mid] < g) lo=mid+1; else hi=mid; }
  segs[g]=lo;
}

// ---------------- one-time edge reorder: linear src + edge_attr (stride 12) -------
__global__ void reorder_kernel(const int* __restrict__ s_eid, const int* __restrict__ src,
                               const float* __restrict__ ea,
                               int* __restrict__ s_src, float* __restrict__ ea_r, int E){
  int i = blockIdx.x*256 + threadIdx.x;
  if (i >= E) return;
  int eid = s_eid[i];
  s_src[i] = src[eid];
  const float* a = ea + (size_t)eid*FBOND;
  float* o = ea_r + (size_t)i*12;
  #pragma unroll
  for (int k=0;k<FBOND;k++) o[k] = a[k];
  o[11] = 0.f;
}

// ---------------- pack weights into MFMA B-fragment layout, split hi/lo -------------
__global__ void packB_kernel(const float* __restrict__ B, short* __restrict__ Bph,
                             short* __restrict__ Bpl, int K, int N){
  int idx = blockIdx.x*256 + threadIdx.x;
  if (idx >= K*N) return;
  int b    = idx & 7;
  int lane = (idx >> 3) & 63;
  int t2   = idx >> 9;
  int KT   = K >> 5;
  int kt   = t2 % KT, nt = t2 / KT;
  int k = kt*32 + ((lane>>4)<<3) + b;
  int n = nt*16 + (lane&15);
  float w = B[(size_t)k*N + n];
  short hi = f2bf(w);
  Bph[idx] = hi;
  Bpl[idx] = f2bf(w - bf2f(hi));
}

// ---------------- pack LSTM [Wih|Whh]^T (K=768, N=1024) + bias, split hi/lo --------
__global__ void packWcat_kernel(const float* __restrict__ Wih, const float* __restrict__ Whh,
                                const float* __restrict__ bih, const float* __restrict__ bhh,
                                short* __restrict__ Wch, short* __restrict__ Wcl,
                                float* __restrict__ bias_c){
  int idx = blockIdx.x*256 + threadIdx.x;
  if (idx < 1024) bias_c[idx] = bih[idx] + bhh[idx];
  if (idx >= 768*1024) return;
  int b    = idx & 7;
  int lane = (idx >> 3) & 63;
  int t2   = idx >> 9;
  const int KT = 24;
  int kt   = t2 % KT, nt = t2 / KT;
  int k = kt*32 + ((lane>>4)<<3) + b;
  int n = nt*16 + (lane&15);
  float w = (k < 512) ? Wih[(size_t)n*512 + k] : Whh[(size_t)n*256 + (k-512)];
  short hi = f2bf(w);
  Wch[idx] = hi;
  Wcl[idx] = f2bf(w - bf2f(hi));
}

// ---------------- fully fused GINE layer ----------------
// 32 nodes/block, 512 threads (8 waves). LDS 67 KB -> 2 blocks/CU.
// phase1: message -> z split in LDS; phase2: GEMM1; phase3: c1 split in LDS
// (aliases z); phase4: GEMM2 + residual epilogue into hout (ping-pong vs hin).
template<bool RE>
__launch_bounds__(512, 4)
__global__ void gine_layer_kernel(
    const float* __restrict__ hin, float* __restrict__ hout,
    const float* __restrict__ ea, const float* __restrict__ bW, const float* __restrict__ bb,
    const int* __restrict__ src, const int* __restrict__ s_eid,
    const int* __restrict__ s_src, const float* __restrict__ ea_r,
    const int* __restrict__ row_ptr, const float* __restrict__ eps, int layer,
    const short* __restrict__ B1h, const short* __restrict__ B1l,
    const short* __restrict__ B2h, const short* __restrict__ B2l,
    const float* __restrict__ sc1v, const float* __restrict__ sh1v,
    const float* __restrict__ sc2v, const float* __restrict__ sh2v){
  __shared__ short smem[33536];        // 67.07 KB
  short* sZh  = smem;                  // [32][264]
  short* sZl  = smem + 8448;
  short* sC1h = smem;                  // [32][520] (aliases z after GEMM1)
  short* sC1l = smem + 16896;
  int t = threadIdx.x;
  int lane = t & 63, wid = t >> 6;
  int lrow = lane & 15, lk8 = (lane>>4)<<3, drow0 = (lane>>4)<<2;
  int m0 = blockIdx.x * 32;
  int c0 = lane*4;

  // ---- phase 1: message pass for this wave's 4 nodes ----
  {
    float4 w[FBOND];
    #pragma unroll
    for (int k=0;k<FBOND;k++) w[k] = *(const float4*)&bW[k*HDIM + c0];
    float4 bb4 = *(const float4*)&bb[c0];
    float epsf = 1.0f + eps[layer];
    for (int nn=0; nn<4; ++nn){
      int nl = wid*4 + nn;
      int node = m0 + nl;
      float4 hv = *(const float4*)&hin[(size_t)node*HDIM + c0];
      float ax = hv.x*epsf, ay = hv.y*epsf, az = hv.z*epsf, aw = hv.w*epsf;
      int s = row_ptr[node], e = row_ptr[node+1];
      float4 hc = make_float4(0,0,0,0), e0 = hc, e1 = hc, e2 = hc;
      if (s < e){
        if (RE){
          hc = *(const float4*)&hin[(size_t)s_src[s]*HDIM + c0];
          const float4* ep = (const float4*)(ea_r + (size_t)s*12);
          e0 = ep[0]; e1 = ep[1]; e2 = ep[2];
        } else {
          int eid = s_eid[s];
          hc = *(const float4*)&hin[(size_t)src[eid]*HDIM + c0];
          const float* er = ea + (size_t)eid*FBOND;
          e0 = make_float4(er[0],er[1],er[2],er[3]);
          e1 = make_float4(er[4],er[5],er[6],er[7]);
          e2 = make_float4(er[8],er[9],er[10],0.f);
        }
      }
      for (int idx=s; idx<e; idx++){
        float4 hn = hc, f0 = e0, f1 = e1, f2 = e2;
        if (idx+1 < e){
          if (RE){
            hn = *(const float4*)&hin[(size_t)s_src[idx+1]*HDIM + c0];
            const float4* ep = (const float4*)(ea_r + (size_t)(idx+1)*12);
            f0 = ep[0]; f1 = ep[1]; f2 = ep[2];
          } else {
            int eid = s_eid[idx+1];
            hn = *(const float4*)&hin[(size_t)src[eid]*HDIM + c0];
            const float* er = ea + (size_t)eid*FBOND;
            f0 = make_float4(er[0],er[1],er[2],er[3]);
            f1 = make_float4(er[4],er[5],er[6],er[7]);
            f2 = make_float4(er[8],er[9],er[10],0.f);
          }
        }
        float ex = bb4.x, ey = bb4.y, ez = bb4.z, ew = bb4.w;
        float ek[FBOND] = {e0.x,e0.y,e0.z,e0.w, e1.x,e1.y,e1.z,e1.w, e2.x,e2.y,e2.z};
        #pragma unroll
        for (int k=0;k<FBOND;k++){
          ex += ek[k]*w[k].x; ey += ek[k]*w[k].y; ez += ek[k]*w[k].z; ew += ek[k]*w[k].w;
        }
        ax += fmaxf(hc.x+ex, 0.f);
        ay += fmaxf(hc.y+ey, 0.f);
        az += fmaxf(hc.z+ez, 0.f);
        aw += fmaxf(hc.w+ew, 0.f);
        hc = hn; e0 = f0; e1 = f1; e2 = f2;
      }
      short4 oh, ol;
      oh.x=f2bf(ax); ol.x=f2bf(ax-bf2f(oh.x));
      oh.y=f2bf(ay); ol.y=f2bf(ay-bf2f(oh.y));
      oh.z=f2bf(az); ol.z=f2bf(az-bf2f(oh.z));
      oh.w=f2bf(aw); ol.w=f2bf(aw-bf2f(oh.w));
      *(short4*)&sZh[nl*264 + c0] = oh;
      *(short4*)&sZl[nl*264 + c0] = ol;
    }
  }
  __syncthreads();

  // ---- phase 2: GEMM1, wave computes c1 cols [wid*64, +64), rows 0..31 ----
  f32x4 acc1[2][4];
  #pragma unroll
  for (int i=0;i<2;i++)
    #pragma unroll
    for (int j=0;j<4;j++) acc1[i][j] = (f32x4){0.f,0.f,0.f,0.f};
  size_t b1base = (size_t)wid*16384 + lane*8;          // nt = wid*4+nf, KT=8
  for (int kt=0; kt<8; ++kt){
    s8v bh[4], bl[4];
    #pragma unroll
    for (int nf=0;nf<4;nf++){
      size_t o = b1base + ((size_t)nf*8 + kt)*512;
      bh[nf] = *(const s8v*)(B1h + o);
      bl[nf] = *(const s8v*)(B1l + o);
    }
    #pragma unroll
    for (int mf=0;mf<2;mf++){
      int rsh = (mf*16 + lrow)*264 + kt*32 + lk8;
      s8v ah = *(const s8v*)&sZh[rsh];
      s8v al = *(const s8v*)&sZl[rsh];
      #pragma unroll
      for (int nf=0;nf<4;nf++){
        acc1[mf][nf] = __builtin_amdgcn_mfma_f32_16x16x32_bf16(ah, bh[nf], acc1[mf][nf],0,0,0);
        acc1[mf][nf] = __builtin_amdgcn_mfma_f32_16x16x32_bf16(ah, bl[nf], acc1[mf][nf],0,0,0);
        acc1[mf][nf] = __builtin_amdgcn_mfma_f32_16x16x32_bf16(al, bh[nf], acc1[mf][nf],0,0,0);
      }
    }
  }
  __syncthreads();   // all waves done reading z

  // ---- phase 3: write c1 = relu(bn1(.)) split into LDS ----
  #pragma unroll
  for (int nf=0;nf<4;nf++){
    int col = wid*64 + nf*16 + lrow;
    float scv = sc1v[col], shv = sh1v[col];
    #pragma unroll
    for (int mf=0;mf<2;mf++){
      int row = mf*16 + drow0;
      #pragma unroll
      for (int r=0;r<4;r++){
        float v = fmaxf(acc1[mf][nf][r]*scv + shv, 0.f);
        short hi = f2bf(v);
        sC1h[(row+r)*520 + col] = hi;
        sC1l[(row+r)*520 + col] = f2bf(v - bf2f(hi));
      }
    }
  }
  __syncthreads();

  // ---- phase 4: GEMM2, wave computes out cols [wid*32, +32), K=512 ----
  f32x4 acc2[2][2];
  #pragma unroll
  for (int i=0;i<2;i++)
    #pragma unroll
    for (int j=0;j<2;j++) acc2[i][j] = (f32x4){0.f,0.f,0.f,0.f};
  size_t b2base = (size_t)wid*16384 + lane*8;          // nt2 = wid*2+nf, KT2=16
  for (int kt=0; kt<16; ++kt){
    size_t o0 = b2base + (size_t)kt*512;
    size_t o1 = b2base + (size_t)(16+kt)*512;
    s8v bh0 = *(const s8v*)(B2h + o0);
    s8v bl0 = *(const s8v*)(B2l + o0);
    s8v bh1 = *(const s8v*)(B2h + o1);
    s8v bl1 = *(const s8v*)(B2l + o1);
    #pragma unroll
    for (int mf=0;mf<2;mf++){
      int rsh = (mf*16 + lrow)*520 + kt*32 + lk8;
      s8v ah = *(const s8v*)&sC1h[rsh];
      s8v al = *(const s8v*)&sC1l[rsh];
      acc2[mf][0] = __builtin_amdgcn_mfma_f32_16x16x32_bf16(ah, bh0, acc2[mf][0],0,0,0);
      acc2[mf][0] = __builtin_amdgcn_mfma_f32_16x16x32_bf16(ah, bl0, acc2[mf][0],0,0,0);
      acc2[mf][0] = __builtin_amdgcn_mfma_f32_16x16x32_bf16(al, bh0, acc2[mf][0],0,0,0);
      acc2[mf][1] = __builtin_amdgcn_mfma_f32_16x16x32_bf16(ah, bh1, acc2[mf][1],0,0,0);
      acc2[mf][1] = __builtin_amdgcn_mfma_f32_16x16x32_bf16(ah, bl1, acc2[mf][1],0,0,0);
      acc2[mf][1] = __builtin_amdgcn_mfma_f32_16x16x32_bf16(al, bh1, acc2[mf][1],0,0,0);
    }
  }

  // ---- epilogue: hout = relu(bn2(.)) + hin ----
  #pragma unroll
  for (int nf=0;nf<2;nf++){
    int col = wid*32 + nf*16 + lrow;
    float scv = sc2v[col], shv = sh2v[col];
    #pragma unroll
    for (int mf=0;mf<2;mf++){
      #pragma unroll
      for (int r=0;r<4;r++){
        int row = m0 + mf*16 + drow0 + r;
        size_t o = (size_t)row*HDIM + col;
        hout[o] = fmaxf(acc2[mf][nf][r]*scv + shv, 0.f) + hin[o];
      }
    }
  }
}

// ---------------- split-bf16 MFMA GEMM (LSTM gates), LDS-staged A ----------------
__launch_bounds__(256)
__global__ void gemm_mfma0(const short* __restrict__ Ah, const short* __restrict__ Al,
                           const short* __restrict__ Bh, const short* __restrict__ Bl,
                           int M, int N, int K,
                           const float* __restrict__ sh, float* __restrict__ Cf){
  __shared__ short As[2][2][64*72];
  int t    = threadIdx.x;
  int lane = t & 63;
  int wid  = t >> 6;
  int m0 = blockIdx.y * 64;
  int n0 = blockIdx.x * 128 + wid * 32;
  int lrow = lane & 15;
  int lk8  = (lane >> 4) << 3;
  int KT = K >> 5;
  int NT = K >> 6;

  f32x4 acc[4][2];
  #pragma unroll
  for (int i=0;i<4;i++)
    #pragma unroll
    for (int j=0;j<2;j++) acc[i][j] = (f32x4){0.f,0.f,0.f,0.f};

  int r0 = t >> 3, c8 = t & 7;
  int gr0 = min(m0 + r0,      M-1);
  int gr1 = min(m0 + r0 + 32, M-1);
  const short* pa0h = Ah + (size_t)gr0*K + c8*8;
  const short* pa0l = Al + (size_t)gr0*K + c8*8;
  const short* pa1h = Ah + (size_t)gr1*K + c8*8;
  const short* pa1l = Al + (size_t)gr1*K + c8*8;
  int wsh0 = r0*72 + c8*8;
  int wsh1 = (r0+32)*72 + c8*8;

  size_t boff = ((size_t)(n0 >> 4) * KT) * 512 + lane*8;

  s8v vh0 = *(const s8v*)(pa0h);
  s8v vh1 = *(const s8v*)(pa1h);
  s8v vl0 = *(const s8v*)(pa0l);
  s8v vl1 = *(const s8v*)(pa1l);
  *(s8v*)&As[0][0][wsh0] = vh0;  *(s8v*)&As[0][0][wsh1] = vh1;
  *(s8v*)&As[0][1][wsh0] = vl0;  *(s8v*)&As[0][1][wsh1] = vl1;
  __syncthreads();

  for (int st=0; st<NT; ++st){
    int cur = st & 1;
    if (st+1 < NT){
      int ko = (st+1)*64;
      vh0 = *(const s8v*)(pa0h + ko);
      vh1 = *(const s8v*)(pa1h + ko);
      vl0 = *(const s8v*)(pa0l + ko);
      vl1 = *(const s8v*)(pa1l + ko);
    }
    #pragma unroll
    for (int ktl=0; ktl<2; ++ktl){
      int kt = st*2 + ktl;
      s8v bh0 = *(const s8v*)(Bh + boff + (size_t)kt*512);
      s8v bl0 = *(const s8v*)(Bl + boff + (size_t)kt*512);
      s8v bh1 = *(const s8v*)(Bh + boff + (size_t)(KT + kt)*512);
      s8v bl1 = *(const s8v*)(Bl + boff + (size_t)(KT + kt)*512);
      int ksh = ktl*32 + lk8;
      #pragma unroll
      for (int mf=0; mf<4; ++mf){
        int rsh = (mf*16 + lrow)*72 + ksh;
        s8v ah = *(const s8v*)&As[cur][0][rsh];
        s8v al = *(const s8v*)&As[cur][1][rsh];
        acc[mf][0] = __builtin_amdgcn_mfma_f32_16x16x32_bf16(ah, bh0, acc[mf][0], 0,0,0);
        acc[mf][0] = __builtin_amdgcn_mfma_f32_16x16x32_bf16(ah, bl0, acc[mf][0], 0,0,0);
        acc[mf][0] = __builtin_amdgcn_mfma_f32_16x16x32_bf16(al, bh0, acc[mf][0], 0,0,0);
        acc[mf][1] = __builtin_amdgcn_mfma_f32_16x16x32_bf16(ah, bh1, acc[mf][1], 0,0,0);
        acc[mf][1] = __builtin_amdgcn_mfma_f32_16x16x32_bf16(ah, bl1, acc[mf][1], 0,0,0);
        acc[mf][1] = __builtin_amdgcn_mfma_f32_16x16x32_bf16(al, bh1, acc[mf][1], 0,0,0);
      }
    }
    if (st+1 < NT){
      int nxt = cur ^ 1;
      *(s8v*)&As[nxt][0][wsh0] = vh0;  *(s8v*)&As[nxt][0][wsh1] = vh1;
      *(s8v*)&As[nxt][1][wsh0] = vl0;  *(s8v*)&As[nxt][1][wsh1] = vl1;
    }
    __syncthreads();
  }

  int drow0 = (lane >> 4) * 4;
  #pragma unroll
  for (int nf=0; nf<2; nf++){
    int col = n0 + nf*16 + lrow;
    float shv = sh[col];
    #pragma unroll
    for (int mf=0; mf<4; mf++){
      #pragma unroll
      for (int r=0; r<4; r++){
        int row = m0 + mf*16 + drow0 + r;
        if (row < M) Cf[(size_t)row*N + col] = acc[mf][nf][r] + shv;
      }
    }
  }
}

// ---------------- BN fold ----------------
__global__ void fold_kernel(
  const float* __restrict__ b1,  const float* __restrict__ g1,  const float* __restrict__ bb1,
  const float* __restrict__ m1,  const float* __restrict__ v1,
  const float* __restrict__ b2,  const float* __restrict__ g2,  const float* __restrict__ bb2,
  const float* __restrict__ m2,  const float* __restrict__ v2,
  const float* __restrict__ cb1, const float* __restrict__ cg1, const float* __restrict__ cbb1,
  const float* __restrict__ cm1, const float* __restrict__ cv1,
  const float* __restrict__ cb2, const float* __restrict__ cg2, const float* __restrict__ cbb2,
  const float* __restrict__ cm2, const float* __restrict__ cv2,
  float* __restrict__ sc1, float* __restrict__ sh1,
  float* __restrict__ sc2, float* __restrict__ sh2,
  float* __restrict__ csc1, float* __restrict__ csh1,
  float* __restrict__ csc2, float* __restrict__ csh2){
  int idx = blockIdx.x*256 + threadIdx.x;
  const int n1 = NLAY*512, n2 = NLAY*256;
  if (idx < n1){
    float s = g1[idx]*rsqrtf(v1[idx]+1e-5f);
    sc1[idx]=s; sh1[idx]=(b1[idx]-m1[idx])*s + bb1[idx];
  } else if (idx < n1+n2){
    int i = idx-n1;
    float s = g2[i]*rsqrtf(v2[i]+1e-5f);
    sc2[i]=s; sh2[i]=(b2[i]-m2[i])*s + bb2[i];
  } else if (idx < n1+n2+256){
    int i = idx-n1-n2;
    float s = cg1[i]*rsqrtf(cv1[i]+1e-5f);
    csc1[i]=s; csh1[i]=(cb1[i]-cm1[i])*s + cbb1[i];
  } else if (idx < n1+n2+256+128){
    int i = idx-n1-n2-256;
    float s = cg2[i]*rsqrtf(cv2[i]+1e-5f);
    csc2[i]=s; csh2[i]=(cb2[i]-cm2[i])*s + cbb2[i];
  }
}

// ---------------- LSTM pointwise (writes q/hst fp32 + split) ----------------
__global__ void lstm_kernel(const float* __restrict__ gates, float* __restrict__ cst,
                            float* __restrict__ qs, short* __restrict__ qsh,
                            short* __restrict__ qsl){
  int idx = blockIdx.x*256 + threadIdx.x;
  int b = idx >> 8, j = idx & 255;
  const float* g = &gates[(size_t)b*1024];
  float ig = sigmoidf_(g[j]);
  float fg = sigmoidf_(g[j+256]);
  float gg = tanhf(g[j+512]);
  float og = sigmoidf_(g[j+768]);
  float c  = fg*cst[idx] + ig*gg;
  float hv = og*tanhf(c);
  cst[idx] = c;
  size_t base = (size_t)b*768;
  qs[base + j]       = hv;
  qs[base + 512 + j] = hv;
  short hi = f2bf(hv);
  short lo = f2bf(hv - bf2f(hi));
  qsh[base + j] = hi;        qsl[base + j] = lo;
  qsh[base + 512 + j] = hi;  qsl[base + 512 + j] = lo;
}

// ---------------- fused attention: ener + segment softmax + weighted r ----------------
__global__ void attn_fused_kernel(const float* __restrict__ h, float* __restrict__ qs,
                                  short* __restrict__ qsh, short* __restrict__ qsl,
                                  const int* __restrict__ segs){
  __shared__ float en[CK];
  __shared__ float red[256];
  __shared__ float hstS[HDIM];
  int g = blockIdx.x, t = threadIdx.x;
  int s = segs[g], e = segs[g+1];
  int lane = t & 63, w = t >> 6;
  if (t < HDIM) hstS[t] = qs[(size_t)g*768 + 512 + t];
  __syncthreads();
  float4 hq = *(const float4*)&hstS[lane*4];
  float m_run = -INFINITY, s_run = 0.f, racc = 0.f;
  for (int base = s; base < e; base += CK){
    int cnt = min(e - base, CK);
    for (int li = w; li < cnt; li += 4){
      float4 hv = *(const float4*)&h[(size_t)(base+li)*HDIM + lane*4];
      float v = hv.x*hq.x + hv.y*hq.y + hv.z*hq.z + hv.w*hq.w;
      for (int o=32; o; o>>=1) v += __shfl_down(v, o);
      if (lane==0) en[li] = v;
    }
    __syncthreads();
    red[t] = (t < cnt) ? en[t] : -INFINITY;
    __syncthreads();
    for (int o=128;o>0;o>>=1){ if (t<o) red[t]=fmaxf(red[t],red[t+o]); __syncthreads(); }
    float nm = fmaxf(m_run, red[0]);
    __syncthreads();
    float ce = (t < cnt) ? expf(en[t]-nm) : 0.f;
    red[t] = ce; __syncthreads();
    for (int o=128;o>0;o>>=1){ if (t<o) red[t]+=red[t+o]; __syncthreads(); }
    float csum = red[0];
    __syncthreads();
    if (t < cnt) en[t] = ce;
    __syncthreads();
    float scale = (m_run == -INFINITY) ? 0.f : expf(m_run - nm);
    s_run = s_run*scale + csum;
    racc  = racc*scale;
    for (int j=0;j<cnt;j++)
      racc += en[j] * h[(size_t)(base+j)*HDIM + t];
    m_run = nm;
    __syncthreads();
  }
  float r = racc / (s_run + 1e-16f);
  size_t o = (size_t)g*768 + 256 + t;
  qs[o] = r;
  short hi = f2bf(r);
  qsh[o] = hi;
  qsl[o] = f2bf(r - bf2f(hi));
}

// ---------------- fused classifier ----------------
__global__ void classifier_kernel(const float* __restrict__ qs,
   const float* __restrict__ cW1, const float* __restrict__ csc1, const float* __restrict__ csh1,
   const float* __restrict__ cW2, const float* __restrict__ csc2, const float* __restrict__ csh2,
   const float* __restrict__ cW3, const float* __restrict__ cb3, float* __restrict__ out){
  __shared__ float sq[512];
  __shared__ float so1[256];
  __shared__ float so2[128];
  __shared__ float fr[256];
  int g = blockIdx.x, t = threadIdx.x;
  sq[t]     = qs[(size_t)g*768 + t];
  sq[t+256] = qs[(size_t)g*768 + 256 + t];
  __syncthreads();
  float acc = 0.f;
  for (int k=0;k<512;k++) acc += sq[k]*cW1[(size_t)k*256 + t];
  so1[t] = fmaxf(acc*csc1[t]+csh1[t], 0.f);
  __syncthreads();
  if (t < 128){
    float a2 = 0.f;
    for (int k=0;k<256;k++) a2 += so1[k]*cW2[(size_t)k*128 + t];
    so2[t] = fmaxf(a2*csc2[t]+csh2[t], 0.f);
  }
  __syncthreads();
  fr[t] = (t<128) ? so2[t]*cW3[t] : 0.f;
  __syncthreads();
  for (int o=128;o>0;o>>=1){ if (t<o) fr[t]+=fr[t+o]; __syncthreads(); }
  if (t==0) out[g] = fr[0] + cb3[0];
}

// ---------------- host ----------------
extern "C" void kernel_launch(void* const* d_in, const int* in_sizes, int n_in,
                              void* d_out, int out_size, void* d_ws, size_t ws_size,
                              hipStream_t stream){
  const float* x         = (const float*)d_in[0];
  const float* edge_attr = (const float*)d_in[1];
  const int*   edge_idx  = (const int*)  d_in[2];
  const int*   batch     = (const int*)  d_in[3];
  const float* atom_W    = (const float*)d_in[4];
  const float* atom_b    = (const float*)d_in[5];
  const float* bond_W    = (const float*)d_in[6];
  const float* bond_b    = (const float*)d_in[7];
  const float* eps       = (const float*)d_in[8];
  const float* W1        = (const float*)d_in[9];
  const float* b1        = (const float*)d_in[10];
  const float* bn1_g     = (const float*)d_in[11];
  const float* bn1_b     = (const float*)d_in[12];
  const float* bn1_m     = (const float*)d_in[13];
  const float* bn1_v     = (const float*)d_in[14];
  const float* W2        = (const float*)d_in[15];
  const float* b2        = (const float*)d_in[16];
  const float* bn_g      = (const float*)d_in[17];
  const float* bn_b      = (const float*)d_in[18];
  const float* bn_m      = (const float*)d_in[19];
  const float* bn_v      = (const float*)d_in[20];
  const float* lstm_Wih  = (const float*)d_in[21];
  const float* lstm_Whh  = (const float*)d_in[22];
  const float* lstm_bih  = (const float*)d_in[23];
  const float* lstm_bhh  = (const float*)d_in[24];
  const float* cW1       = (const float*)d_in[25];
  const float* cb1       = (const float*)d_in[26];
  const float* cbn1_g    = (const float*)d_in[27];
  const float* cbn1_b    = (const float*)d_in[28];
  const float* cbn1_m    = (const float*)d_in[29];
  const float* cbn1_v    = (const float*)d_in[30];
  const float* cW2       = (const float*)d_in[31];
  const float* cb2       = (const float*)d_in[32];
  const float* cbn2_g    = (const float*)d_in[33];
  const float* cbn2_b    = (const float*)d_in[34];
  const float* cbn2_m    = (const float*)d_in[35];
  const float* cbn2_v    = (const float*)d_in[36];
  const float* cW3       = (const float*)d_in[37];
  const float* cb3       = (const float*)d_in[38];

  const int* src = edge_idx;
  const int* dst = edge_idx + N_EDGES;

  char* ws = (char*)d_ws;
  size_t off = 0;
  auto alloc = [&](size_t bytes)->void*{
    void* p = ws + off; off += (bytes + 255) & ~(size_t)255; return p;
  };
  float* h0      = (float*)alloc((size_t)N_NODES*HDIM*4);     // 102.4 MB
  float* h1      = (float*)alloc((size_t)N_NODES*HDIM*4);     // 102.4 MB
  int*   row_ptr = (int*)  alloc((size_t)(N_NODES+1)*4);
  int*   cursor  = (int*)  alloc((size_t)N_NODES*4);
  int*   s_eid   = (int*)  alloc((size_t)N_EDGES*4);
  int*   segs    = (int*)  alloc((size_t)(NB+1)*4);
  short* W1ph    = (short*)alloc((size_t)NLAY*HDIM*2*HDIM*2);
  short* W1pl    = (short*)alloc((size_t)NLAY*HDIM*2*HDIM*2);
  short* W2ph    = (short*)alloc((size_t)NLAY*HDIM*2*HDIM*2);
  short* W2pl    = (short*)alloc((size_t)NLAY*HDIM*2*HDIM*2);
  float* sc1     = (float*)alloc(NLAY*512*4);
  float* sh1     = (float*)alloc(NLAY*512*4);
  float* sc2     = (float*)alloc(NLAY*256*4);
  float* sh2     = (float*)alloc(NLAY*256*4);
  float* csc1    = (float*)alloc(256*4);
  float* csh1    = (float*)alloc(256*4);
  float* csc2    = (float*)alloc(128*4);
  float* csh2    = (float*)alloc(128*4);

  if (off >= ws_size){
    sentinel_kernel<<<(out_size+255)/256, 256, 0, stream>>>((float*)d_out, out_size);
    return;
  }
  size_t remain = ws_size - off;

  // optional edge reorder buffers (20.8 MB)
  const size_t RE_BYTES = (((size_t)N_EDGES*4 + 255)&~(size_t)255)
                        + (((size_t)N_EDGES*12*4 + 255)&~(size_t)255);
  bool use_re = (remain >= RE_BYTES);
  int*   s_src = nullptr;
  float* ea_r  = nullptr;
  if (use_re){
    s_src = (int*)  alloc((size_t)N_EDGES*4);
    ea_r  = (float*)alloc((size_t)N_EDGES*12*4);
  }

  // Set2Set scratch aliases h0 (dead after layer 4 consumed it).
  char*  zb      = (char*)(void*)h0;
  float* gates   = (float*)zb;                          // 16.78 MB
  float* qs      = (float*)(zb + 16777216);             // 12.58 MB
  float* cst     = (float*)(zb + 29360128);             //  4.19 MB
  short* qsh     = (short*)(zb + 33554432);             //  6.29 MB
  short* qsl     = (short*)(zb + 39845888);             //  6.29 MB
  short* Wch     = (short*)(zb + 46137344);             //  1.57 MB
  short* Wcl     = (short*)(zb + 47710208);             //  1.57 MB
  float* bias_c  = (float*)(zb + 49283072);             //  4 KB

  // ---- prep: fold BN+bias, pack GNN weights (split hi/lo) ----
  fold_kernel<<<(NLAY*512+NLAY*256+256+128+255)/256, 256, 0, stream>>>(
      b1, bn1_g, bn1_b, bn1_m, bn1_v,
      b2, bn_g,  bn_b,  bn_m,  bn_v,
      cb1, cbn1_g, cbn1_b, cbn1_m, cbn1_v,
      cb2, cbn2_g, cbn2_b, cbn2_m, cbn2_v,
      sc1, sh1, sc2, sh2, csc1, csh1, csc2, csh2);
  for (int l=0; l<NLAY; l++){
    packB_kernel<<<(HDIM*2*HDIM)/256, 256, 0, stream>>>(
        W1 + (size_t)l*HDIM*2*HDIM, W1ph + (size_t)l*HDIM*2*HDIM, W1pl + (size_t)l*HDIM*2*HDIM, HDIM, 2*HDIM);
    packB_kernel<<<(HDIM*2*HDIM)/256, 256, 0, stream>>>(
        W2 + (size_t)l*HDIM*2*HDIM, W2ph + (size_t)l*HDIM*2*HDIM, W2pl + (size_t)l*HDIM*2*HDIM, 2*HDIM, HDIM);
  }

  // ---- embeddings ----
  atom_embed_kernel<<<N_NODES/8, 256, 0, stream>>>(x, atom_W, atom_b, h0);

  // ---- CSR by dst + batch segment starts (+ optional edge reorder) ----
  hipMemsetAsync(cursor, 0, (size_t)N_NODES*4, stream);
  count_kernel<<<(N_EDGES+255)/256, 256, 0, stream>>>(dst, cursor, N_EDGES);
  scan_kernel<<<1, 1024, 0, stream>>>(cursor, row_ptr, N_NODES);
  hipMemcpyAsync(cursor, row_ptr, (size_t)N_NODES*4, hipMemcpyDeviceToDevice, stream);
  fill_kernel<<<(N_EDGES+255)/256, 256, 0, stream>>>(dst, cursor, s_eid, N_EDGES);
  segstart_kernel<<<(NB+256)/256, 256, 0, stream>>>(batch, segs, N_NODES, NB);
  if (use_re)
    reorder_kernel<<<(N_EDGES+255)/256, 256, 0, stream>>>(s_eid, src, edge_attr, s_src, ea_r, N_EDGES);

  // ---- GINE layers: fully fused (msg + MLP), h ping-pong ----
  const int gx = N_NODES/32;   // 3125, exact
  for (int l=0; l<NLAY; l++){
    const float* hi_ = (l&1) ? h1 : h0;
    float*       ho_ = (l&1) ? h0 : h1;
    if (use_re)
      gine_layer_kernel<true><<<gx, 512, 0, stream>>>(
          hi_, ho_, edge_attr, bond_W, bond_b, src, s_eid, s_src, ea_r,
          row_ptr, eps, l,
          W1ph + (size_t)l*HDIM*2*HDIM, W1pl + (size_t)l*HDIM*2*HDIM,
          W2ph + (size_t)l*HDIM*2*HDIM, W2pl + (size_t)l*HDIM*2*HDIM,
          sc1 + l*512, sh1 + l*512, sc2 + l*256, sh2 + l*256);
    else
      gine_layer_kernel<false><<<gx, 512, 0, stream>>>(
          hi_, ho_, edge_attr, bond_W, bond_b, src, s_eid, s_src, ea_r,
          row_ptr, eps, l,
          W1ph + (size_t)l*HDIM*2*HDIM, W1pl + (size_t)l*HDIM*2*HDIM,
          W2ph + (size_t)l*HDIM*2*HDIM, W2pl + (size_t)l*HDIM*2*HDIM,
          sc1 + l*512, sh1 + l*512, sc2 + l*256, sh2 + l*256);
  }
  const float* hf = h1;   // NLAY=5 (odd) -> final h in h1

  // ---- Set2Set (scratch aliases h0, now dead) ----
  packWcat_kernel<<<(768*1024+255)/256, 256, 0, stream>>>(lstm_Wih, lstm_Whh, lstm_bih, lstm_bhh,
                                                          Wch, Wcl, bias_c);
  hipMemsetAsync(qsh, 0, (size_t)NB*768*2, stream);
  hipMemsetAsync(qsl, 0, (size_t)NB*768*2, stream);
  hipMemsetAsync(cst, 0, (size_t)NB*HDIM*4, stream);
  for (int sstep=0; sstep<3; sstep++){
    gemm_mfma0<<<dim3(1024/128, NB/64), 256, 0, stream>>>(
        qsh, qsl, Wch, Wcl, NB, 1024, 768, bias_c, gates);
    lstm_kernel<<<(NB*HDIM)/256, 256, 0, stream>>>(gates, cst, qs, qsh, qsl);
    attn_fused_kernel<<<NB, 256, 0, stream>>>(hf, qs, qsh, qsl, segs);
  }

  // ---- classifier ----
  classifier_kernel<<<NB, 256, 0, stream>>>(qs, cW1, csc1, csh1, cW2, csc2, csh2,
                                            cW3, cb3, (float*)d_out);
}